// Round 2
// baseline (231.054 us; speedup 1.0000x reference)
//
#include <hip/hip_runtime.h>
#include <hip/hip_bf16.h>

typedef unsigned short u16;
typedef __attribute__((ext_vector_type(8))) unsigned short u16x8;
typedef __attribute__((ext_vector_type(4))) float f32x4;

__device__ __forceinline__ float b2f(u16 v) {
    union { unsigned int u; float f; } c; c.u = ((unsigned int)v) << 16; return c.f;
}
__device__ __forceinline__ u16 f2b(float f) {
    union { unsigned int u; float f; } c; c.f = f;
    unsigned int u = c.u;
    u += 0x7FFFu + ((u >> 16) & 1u);   // round-to-nearest-even
    return (u16)(u >> 16);
}

// 32x32-tile transpose, one 128x128 plane per blockIdx.z (z = b*128 + c).
// A[r][s] at src[b*sb + c*sc + r*sstr + s] -> dst[b*db + c*dc + s*dstr + r].
__global__ __launch_bounds__(256) void transpose_f2b(
    const float* __restrict__ src, u16* __restrict__ dst,
    int sb, int sc, int sstr, int db, int dc, int dstr) {
  __shared__ u16 tile[32][33];
  int z = blockIdx.z, b = z >> 7, c = z & 127;
  const float* s = src + b * sb + c * sc;
  u16* d = dst + b * db + c * dc;
  int tx = threadIdx.x, ty = threadIdx.y;
  int r0 = blockIdx.y * 32, c0 = blockIdx.x * 32;
#pragma unroll
  for (int k = 0; k < 4; k++)
    tile[ty + k * 8][tx] = f2b(s[(r0 + ty + k * 8) * sstr + c0 + tx]);
  __syncthreads();
#pragma unroll
  for (int k = 0; k < 4; k++)
    d[(c0 + ty + k * 8) * dstr + r0 + tx] = tile[tx][ty + k * 8];
}

__global__ __launch_bounds__(256) void transpose_b2f(
    const u16* __restrict__ src, float* __restrict__ dst,
    int sb, int sc, int sstr, int db, int dc, int dstr) {
  __shared__ u16 tile[32][33];
  int z = blockIdx.z, b = z >> 7, c = z & 127;
  const u16* s = src + b * sb + c * sc;
  float* d = dst + b * db + c * dc;
  int tx = threadIdx.x, ty = threadIdx.y;
  int r0 = blockIdx.y * 32, c0 = blockIdx.x * 32;
#pragma unroll
  for (int k = 0; k < 4; k++)
    tile[ty + k * 8][tx] = s[(r0 + ty + k * 8) * sstr + c0 + tx];
  __syncthreads();
#pragma unroll
  for (int k = 0; k < 4; k++)
    d[(c0 + ty + k * 8) * dstr + r0 + tx] = b2f(tile[tx][ty + k * 8]);
}

// K1: per-slice GEMM  kqv[n][o][h] = BN_o( sum_c w[o][c] * xt[n][c][h] )
// block = one n (256 threads), o processed in 4 tiles of 64.
__global__ __launch_bounds__(256) void kqv_gemm(
    const u16* __restrict__ xt, const float* __restrict__ wmat,
    const float* __restrict__ gam, const float* __restrict__ bet,
    const float* __restrict__ mea, const float* __restrict__ var,
    float* __restrict__ kqv) {
  __shared__ __align__(16) u16 xs[16384];       // [c=128][h=128] bf16
  __shared__ float wt[64 * 130];                // padded stride vs bank conflicts
  __shared__ float invb[256], biasb[256];
  int n = blockIdx.x, tid = threadIdx.x;
  const u16* xsl = xt + n * 16384;
  for (int i = tid; i < 2048; i += 256)
    ((u16x8*)xs)[i] = ((const u16x8*)xsl)[i];
  {
    float g = gam[tid], bb = bet[tid], mm = mea[tid], vv = var[tid];
    float inv = g * rsqrtf(vv + 1e-5f);
    invb[tid] = inv;
    biasb[tid] = bb - mm * inv;
  }
  int tx = tid & 15, ty = tid >> 4;             // tx -> h-octet, ty -> o-quad
  for (int ot = 0; ot < 4; ot++) {
    __syncthreads();
    for (int i = tid; i < 8192; i += 256) {
      int o = i >> 7, c = i & 127;
      wt[o * 130 + c] = wmat[(ot * 64 + o) * 128 + c];
    }
    __syncthreads();
    float acc[4][8];
#pragma unroll
    for (int j = 0; j < 4; j++)
#pragma unroll
      for (int i = 0; i < 8; i++) acc[j][i] = 0.f;
    for (int c = 0; c < 128; c++) {
      u16x8 xv = ((const u16x8*)(xs + c * 128))[tx];
      float xf[8];
#pragma unroll
      for (int i = 0; i < 8; i++) xf[i] = b2f(xv[i]);
#pragma unroll
      for (int j = 0; j < 4; j++) {
        float w = wt[(ty * 4 + j) * 130 + c];
#pragma unroll
        for (int i = 0; i < 8; i++) acc[j][i] += w * xf[i];
      }
    }
#pragma unroll
    for (int j = 0; j < 4; j++) {
      int o = ot * 64 + ty * 4 + j;
      float inv = invb[o], bia = biasb[o];
      float* dst = kqv + (n * 256 + o) * 128 + tx * 8;
      f32x4 v0, v1;
#pragma unroll
      for (int i = 0; i < 4; i++) { v0[i] = acc[j][i] * inv + bia; v1[i] = acc[j][i + 4] * inv + bia; }
      *(f32x4*)dst = v0;
      *(f32x4*)(dst + 4) = v1;
    }
  }
}

// K2: fused qk/qr/kr + BN-affine + online softmax + (v + v_enc) PV.
// One block per (head, n); thread x owns output row x.
__device__ __forceinline__ int rslot(int c4, int r) { return (c4 ^ ((r >> 1) & 3)) << 3; }

__global__ __launch_bounds__(128) void attn_fused(
    const float* __restrict__ kqv, const float* __restrict__ rel,
    const float* __restrict__ lg, const float* __restrict__ lb,
    const float* __restrict__ lm, const float* __restrict__ lv,
    u16* __restrict__ otmp) {
  __shared__ __align__(16) float k_t[128][8];
  __shared__ __align__(16) float q_t[128][8];
  __shared__ __align__(16) float v_t[128][16];
  __shared__ __align__(16) u16 rel_t[255][32];  // row r: 4 chunks of 8 bf16, chunk pos = c4 ^ ((r>>1)&3)
  int head = blockIdx.x, n = blockIdx.y, x = threadIdx.x;
  const float* base = kqv + (n * 256 + head * 32) * 128;
#pragma unroll
  for (int j = 0; j < 8; j++)  k_t[x][j] = base[j * 128 + x];
#pragma unroll
  for (int j = 0; j < 8; j++)  q_t[x][j] = base[(8 + j) * 128 + x];
#pragma unroll
  for (int j = 0; j < 16; j++) v_t[x][j] = base[(16 + j) * 128 + x];
  for (int d = 0; d < 32; d++) {
    int c4 = d >> 3;
    for (int r = x; r < 255; r += 128)
      rel_t[r][rslot(c4, r) + (d & 7)] = f2b(rel[d * 255 + r]);
  }
  float a0 = lg[head]      * rsqrtf(lv[head] + 1e-5f);
  float a1 = lg[8 + head]  * rsqrtf(lv[8 + head] + 1e-5f);
  float a2 = lg[16 + head] * rsqrtf(lv[16 + head] + 1e-5f);
  float bsum = (lb[head]      - lm[head]      * a0)
             + (lb[8 + head]  - lm[8 + head]  * a1)
             + (lb[16 + head] - lm[16 + head] * a2);
  __syncthreads();
  float qreg[8];
#pragma unroll
  for (int d = 0; d < 8; d++) qreg[d] = q_t[x][d];
  float m = -1e30f, l = 0.f, acc[16];
#pragma unroll
  for (int d = 0; d < 16; d++) acc[d] = 0.f;
  for (int y = 0; y < 128; y++) {
    f32x4 k0 = *(const f32x4*)&k_t[y][0];
    f32x4 k1 = *(const f32x4*)&k_t[y][4];
    float kc[8];
#pragma unroll
    for (int i = 0; i < 4; i++) { kc[i] = k0[i]; kc[4 + i] = k1[i]; }
    int r1 = y - x + 127, r2 = x - y + 127;
    u16x8 qe  = *(const u16x8*)&rel_t[r1][rslot(0, r1)];
    u16x8 ke  = *(const u16x8*)&rel_t[r2][rslot(1, r2)];
    u16x8 ve0 = *(const u16x8*)&rel_t[r1][rslot(2, r1)];
    u16x8 ve1 = *(const u16x8*)&rel_t[r1][rslot(3, r1)];
    float s0 = 0.f, s1 = 0.f, s2 = 0.f;
#pragma unroll
    for (int d = 0; d < 8; d++) {
      s0 += qreg[d] * kc[d];
      s1 += qreg[d] * b2f(qe[d]);
      s2 += kc[d]   * b2f(ke[d]);
    }
    float logit = a0 * s0 + a1 * s1 + a2 * s2 + bsum;
    float mn = fmaxf(m, logit);
    float scl = __expf(m - mn);
    float p   = __expf(logit - mn);
    l = l * scl + p;
    f32x4 v0 = *(const f32x4*)&v_t[y][0];
    f32x4 v1 = *(const f32x4*)&v_t[y][4];
    f32x4 v2 = *(const f32x4*)&v_t[y][8];
    f32x4 v3 = *(const f32x4*)&v_t[y][12];
    float vc[16];
#pragma unroll
    for (int i = 0; i < 4; i++) { vc[i] = v0[i]; vc[4 + i] = v1[i]; vc[8 + i] = v2[i]; vc[12 + i] = v3[i]; }
#pragma unroll
    for (int d = 0; d < 16; d++) {
      float vv = vc[d] + b2f(d < 8 ? ve0[d] : ve1[d - 8]);
      acc[d] = acc[d] * scl + p * vv;
    }
    m = mn;
  }
  float rl = 1.f / l;
  u16* dst = otmp + ((n * 8 + head) * 16) * 128 + x;
#pragma unroll
  for (int d = 0; d < 16; d++) dst[d * 128] = f2b(acc[d] * rl);
}

extern "C" void kernel_launch(void* const* d_in, const int* in_sizes, int n_in,
                              void* d_out, int out_size, void* d_ws, size_t ws_size,
                              hipStream_t stream) {
  const float* x      = (const float*)d_in[0];
  const float* kqv_w  = (const float*)d_in[1];
  const float* kqv_g  = (const float*)d_in[2];
  const float* kqv_b  = (const float*)d_in[3];
  const float* kqv_m  = (const float*)d_in[4];
  const float* kqv_v  = (const float*)d_in[5];
  const float* lg     = (const float*)d_in[6];
  const float* lb     = (const float*)d_in[7];
  const float* lm     = (const float*)d_in[8];
  const float* lv     = (const float*)d_in[9];
  const float* rel    = (const float*)d_in[10];
  float* out = (float*)d_out;

  u16*   xt   = (u16*)d_ws;                                        //  8 MiB bf16
  float* kqv  = (float*)((char*)d_ws + (8u << 20));                // 32 MiB fp32
  u16*   otmp = (u16*)((char*)d_ws + (40u << 20));                 //  8 MiB bf16

  // x (B,C,H,W) fp32 -> xt[(b*W+w)][c][h] bf16
  transpose_f2b<<<dim3(4, 4, 256), dim3(32, 8), 0, stream>>>(
      x, xt, 2097152, 16384, 128, 2097152, 128, 16384);
  kqv_gemm<<<dim3(256), dim3(256), 0, stream>>>(
      xt, kqv_w, kqv_g, kqv_b, kqv_m, kqv_v, kqv);
  attn_fused<<<dim3(8, 256), dim3(128), 0, stream>>>(
      kqv, rel, lg, lb, lm, lv, otmp);
  // otmp[b][w][c][x] bf16 -> out[b][c][x][w] fp32
  transpose_b2f<<<dim3(4, 4, 256), dim3(32, 8), 0, stream>>>(
      otmp, out, 2097152, 128, 16384, 2097152, 16384, 128);
}

// Round 3
// 183.732 us; speedup vs baseline: 1.2576x; 1.2576x over previous
//
#include <hip/hip_runtime.h>

typedef unsigned short u16;
typedef __attribute__((ext_vector_type(8))) unsigned short u16x8;
typedef __attribute__((ext_vector_type(8))) short s8;      // 8 bf16 (A/B frag)
typedef _Float16 h8 __attribute__((ext_vector_type(8)));   // 8 f16  (A/B frag)
typedef __attribute__((ext_vector_type(4))) float f32x4;

__device__ __forceinline__ float b2f(u16 v) {
    union { unsigned int u; float f; } c; c.u = ((unsigned int)v) << 16; return c.f;
}
__device__ __forceinline__ u16 f2b(float f) {
    union { unsigned int u; float f; } c; c.f = f;
    unsigned int u = c.u;
    u += 0x7FFFu + ((u >> 16) & 1u);
    return (u16)(u >> 16);
}

// ---------- transposes ----------
__global__ __launch_bounds__(256) void transpose_f2b(
    const float* __restrict__ src, u16* __restrict__ dst,
    int sb, int sc, int sstr, int db, int dc, int dstr) {
  __shared__ u16 tile[32][33];
  int z = blockIdx.z, b = z >> 7, c = z & 127;
  const float* s = src + b * sb + c * sc;
  u16* d = dst + b * db + c * dc;
  int tx = threadIdx.x, ty = threadIdx.y;
  int r0 = blockIdx.y * 32, c0 = blockIdx.x * 32;
#pragma unroll
  for (int k = 0; k < 4; k++)
    tile[ty + k * 8][tx] = f2b(s[(r0 + ty + k * 8) * sstr + c0 + tx]);
  __syncthreads();
#pragma unroll
  for (int k = 0; k < 4; k++)
    d[(c0 + ty + k * 8) * dstr + r0 + tx] = tile[tx][ty + k * 8];
}

__global__ __launch_bounds__(256) void transpose_h2f(
    const u16* __restrict__ src, float* __restrict__ dst,
    int sb, int sc, int sstr, int db, int dc, int dstr) {
  __shared__ u16 tile[32][33];
  int z = blockIdx.z, b = z >> 7, c = z & 127;
  const u16* s = src + b * sb + c * sc;
  float* d = dst + b * db + c * dc;
  int tx = threadIdx.x, ty = threadIdx.y;
  int r0 = blockIdx.y * 32, c0 = blockIdx.x * 32;
#pragma unroll
  for (int k = 0; k < 4; k++)
    tile[ty + k * 8][tx] = s[(r0 + ty + k * 8) * sstr + c0 + tx];
  __syncthreads();
#pragma unroll
  for (int k = 0; k < 4; k++) {
    u16 hv = tile[tx][ty + k * 8];
    d[(c0 + ty + k * 8) * dstr + r0 + tx] = (float)(*(const _Float16*)&hv);
  }
}

// ---------- K1: kqv GEMM + BN (unchanged from round 2) ----------
__global__ __launch_bounds__(256) void kqv_gemm(
    const u16* __restrict__ xt, const float* __restrict__ wmat,
    const float* __restrict__ gam, const float* __restrict__ bet,
    const float* __restrict__ mea, const float* __restrict__ var,
    float* __restrict__ kqv) {
  __shared__ __attribute__((aligned(16))) u16 xs[16384];
  __shared__ float wt[64 * 130];
  __shared__ float invb[256], biasb[256];
  int n = blockIdx.x, tid = threadIdx.x;
  const u16* xsl = xt + n * 16384;
  for (int i = tid; i < 2048; i += 256)
    ((u16x8*)xs)[i] = ((const u16x8*)xsl)[i];
  {
    float g = gam[tid], bb = bet[tid], mm = mea[tid], vv = var[tid];
    float inv = g * rsqrtf(vv + 1e-5f);
    invb[tid] = inv;
    biasb[tid] = bb - mm * inv;
  }
  int tx = tid & 15, ty = tid >> 4;
  for (int ot = 0; ot < 4; ot++) {
    __syncthreads();
    for (int i = tid; i < 8192; i += 256) {
      int o = i >> 7, c = i & 127;
      wt[o * 130 + c] = wmat[(ot * 64 + o) * 128 + c];
    }
    __syncthreads();
    float acc[4][8];
#pragma unroll
    for (int j = 0; j < 4; j++)
#pragma unroll
      for (int i = 0; i < 8; i++) acc[j][i] = 0.f;
    for (int c = 0; c < 128; c++) {
      u16x8 xv = ((const u16x8*)(xs + c * 128))[tx];
      float xf[8];
#pragma unroll
      for (int i = 0; i < 8; i++) xf[i] = b2f(xv[i]);
#pragma unroll
      for (int j = 0; j < 4; j++) {
        float w = wt[(ty * 4 + j) * 130 + c];
#pragma unroll
        for (int i = 0; i < 8; i++) acc[j][i] += w * xf[i];
      }
    }
#pragma unroll
    for (int j = 0; j < 4; j++) {
      int o = ot * 64 + ty * 4 + j;
      float inv = invb[o], bia = biasb[o];
      float* dst = kqv + (n * 256 + o) * 128 + tx * 8;
      f32x4 v0, v1;
#pragma unroll
      for (int i = 0; i < 4; i++) { v0[i] = acc[j][i] * inv + bia; v1[i] = acc[j][i + 4] * inv + bia; }
      *(f32x4*)dst = v0;
      *(f32x4*)(dst + 4) = v1;
    }
  }
}

// ---------- K2: MFMA attention ----------
// LDS map (bytes)
#define O_QH 0       // qA hi [128][8] u16, +x*16+d*2
#define O_KH 4096    // kA hi (lo at +2048 for both)
#define O_EQH 8192   // EqB hi [256][8] u16, +r*16+d*2 (lo at +4096)
#define O_EKH 16384
#define O_VB 24576   // f16 [16][128] swz: +d*256+(((y>>3)^(d&7))<<4)+(y&7)*2
#define O_VEB 28672  // f16 [16][256] swz: +d*512+(((r>>3)^(d&7))<<4)+(r&7)*2
#define O_S 36864    // f16 [128][128] swz: +x*256+(((y>>3)^(x&7))<<4)+(y&7)*2
#define O_RS 69632   // f16 [16][160]: +row*320+col*2   (5120 B, phase-shared)
#define O_SKEW 69632 // wave w: +w*1024+xx*64+j*2
#define O_SMAX 69632
#define O_SSUM 70656
#define O_RL 74752   // [128] f32
#define LDS_BYTES 75264

__global__ __launch_bounds__(256, 2) void attn_mfma(
    const float* __restrict__ kqv, const float* __restrict__ rel,
    const float* __restrict__ lg, const float* __restrict__ lb,
    const float* __restrict__ lm, const float* __restrict__ lv,
    _Float16* __restrict__ otmp) {
  __shared__ __attribute__((aligned(16))) char smem[LDS_BYTES];
  const int tid = threadIdx.x;
  const int head = blockIdx.x, n = blockIdx.y;
  const int lane = tid & 63, wv = tid >> 6;
  const int g = lane >> 4, l15 = lane & 15;

  // ---- stage kqv slice: k,q -> hi/lo bf16 A-tables; v -> f16 ----
  const long kbase = ((long)(n * 256 + head * 32)) * 128;
  for (int i = tid; i < 4096; i += 256) {
    int o = i >> 7, p = i & 127;
    float val = kqv[kbase + o * 128 + p];
    if (o < 16) {
      u16 hi = f2b(val);
      u16 lo = f2b(val - b2f(hi));
      int off = (o < 8) ? O_KH : O_QH;
      int d = o & 7;
      *(u16*)(smem + off + p * 16 + d * 2) = hi;
      *(u16*)(smem + off + 2048 + p * 16 + d * 2) = lo;
    } else {
      int d = o - 16;
      *(_Float16*)(smem + O_VB + d * 256 + ((((p >> 3) ^ (d & 7))) << 4) + (p & 7) * 2) = (_Float16)val;
    }
  }
  // ---- stage rel tables (row/col 255 zero-padded) ----
  for (int i = tid; i < 8192; i += 256) {
    int d = i >> 8, r = i & 255;
    float val = (r < 255) ? rel[d * 255 + r] : 0.f;
    if (d < 16) {
      u16 hi = f2b(val);
      u16 lo = f2b(val - b2f(hi));
      int off = (d < 8) ? O_EQH : O_EKH;
      int dd = d & 7;
      *(u16*)(smem + off + r * 16 + dd * 2) = hi;
      *(u16*)(smem + off + 4096 + r * 16 + dd * 2) = lo;
    } else {
      int dd = d - 16;
      *(_Float16*)(smem + O_VEB + dd * 512 + ((((r >> 3) ^ (dd & 7))) << 4) + (r & 7) * 2) = (_Float16)val;
    }
  }
  float a0 = lg[head] * rsqrtf(lv[head] + 1e-5f);
  float a1 = lg[8 + head] * rsqrtf(lv[8 + head] + 1e-5f);
  float a2 = lg[16 + head] * rsqrtf(lv[16 + head] + 1e-5f);
  float bsum = (lb[head] - lm[head] * a0) + (lb[8 + head] - lm[8 + head] * a1)
             + (lb[16 + head] - lm[16 + head] * a2);
  __syncthreads();

  // hi/lo k-slot packing: A planes (hi,lo,hi,lo), B planes (hi,hi,lo,lo)
  const int selA_q = O_QH + ((g & 1) ? 2048 : 0);
  const int selA_k = O_KH + ((g & 1) ? 2048 : 0);
  const int selB_k = O_KH + ((g >> 1) ? 2048 : 0);
  const int selB_eq = O_EQH + ((g >> 1) ? 4096 : 0);
  const int selB_ek = O_EKH + ((g >> 1) ? 4096 : 0);
  const f32x4 zero4 = {0.f, 0.f, 0.f, 0.f};

  // ---- phase S0: S = a0*(q.k) + bsum ----
#pragma unroll
  for (int xi = 0; xi < 2; xi++) {
    int X0 = (2 * wv + xi) * 16;
    s8 afrag = *(const s8*)(smem + selA_q + (X0 + l15) * 16);
    for (int yt = 0; yt < 8; yt++) {
      int Y0 = yt * 16;
      s8 bfrag = *(const s8*)(smem + selB_k + (Y0 + l15) * 16);
      f32x4 dD = __builtin_amdgcn_mfma_f32_16x16x32_bf16(afrag, bfrag, zero4, 0, 0, 0);
      int y = Y0 + l15;
#pragma unroll
      for (int i = 0; i < 4; i++) {
        int x = X0 + 4 * g + i;
        *(_Float16*)(smem + O_S + x * 256 + ((((y >> 3) ^ (x & 7))) << 4) + (y & 7) * 2) =
            (_Float16)(a0 * dD[i] + bsum);
      }
    }
  }
  __syncthreads();

  // ---- phase R1 strips: S[x][y] += a1 * (q.Eq)[x][y-x+127] ----
  for (int Xs = 0; Xs < 8; Xs++) {
    int X0 = Xs * 16, rb = 112 - X0;
    s8 afrag = *(const s8*)(smem + selA_q + (X0 + l15) * 16);
    for (int k = wv; k < 9; k += 4) {
      int r0 = rb + 16 * k;
      s8 bfrag = *(const s8*)(smem + selB_eq + (r0 + l15) * 16);
      f32x4 dD = __builtin_amdgcn_mfma_f32_16x16x32_bf16(afrag, bfrag, zero4, 0, 0, 0);
#pragma unroll
      for (int i = 0; i < 4; i++)
        *(_Float16*)(smem + O_RS + (4 * g + i) * 320 + (16 * k + l15) * 2) = (_Float16)dD[i];
    }
    __syncthreads();
    {
      int xx = tid & 15, oct = tid >> 4;
      int x = X0 + xx;
      int caddr = O_S + x * 256 + (((oct ^ (x & 7))) << 4);
      h8 cur = *(const h8*)(smem + caddr);
#pragma unroll
      for (int jj = 0; jj < 8; jj++) {
        int idx = 8 * oct + jj - xx + 15;
        float rv = (float)*(const _Float16*)(smem + O_RS + xx * 320 + idx * 2);
        cur[jj] = (_Float16)((float)cur[jj] + a1 * rv);
      }
      *(h8*)(smem + caddr) = cur;
    }
    __syncthreads();
  }

  // ---- phase R2 strips: S[x][y] += a2 * (k.Ek)[y][x-y+127] ----
  for (int Ys = 0; Ys < 8; Ys++) {
    int Y0 = Ys * 16, rb = 112 - Y0;
    s8 afrag = *(const s8*)(smem + selA_k + (Y0 + l15) * 16);
    for (int k = wv; k < 9; k += 4) {
      int r0 = rb + 16 * k;
      s8 bfrag = *(const s8*)(smem + selB_ek + (r0 + l15) * 16);
      f32x4 dD = __builtin_amdgcn_mfma_f32_16x16x32_bf16(afrag, bfrag, zero4, 0, 0, 0);
#pragma unroll
      for (int i = 0; i < 4; i++)
        *(_Float16*)(smem + O_RS + (4 * g + i) * 320 + (16 * k + l15) * 2) = (_Float16)dD[i];
    }
    __syncthreads();
    {
      int x = tid & 127, half = tid >> 7;
      int chunk = 2 * Ys + half;
      int caddr = O_S + x * 256 + (((chunk ^ (x & 7))) << 4);
      h8 cur = *(const h8*)(smem + caddr);
#pragma unroll
      for (int q = 0; q < 8; q++) {
        int yy = 8 * half + q;
        int idx = x - yy + 15;
        float rv = (float)*(const _Float16*)(smem + O_RS + yy * 320 + idx * 2);
        cur[q] = (_Float16)((float)cur[q] + a2 * rv);
      }
      *(h8*)(smem + caddr) = cur;
    }
    __syncthreads();
  }

  // ---- softmax (two threads per row), P (unnormalized) in place, rl[] ----
  {
    int x = tid & 127, half = tid >> 7;
    float m = -1e30f;
    for (int cc = 0; cc < 8; cc++) {
      int chunk = 8 * half + cc;
      h8 sv = *(const h8*)(smem + O_S + x * 256 + (((chunk ^ (x & 7))) << 4));
#pragma unroll
      for (int j = 0; j < 8; j++) m = fmaxf(m, (float)sv[j]);
    }
    *(float*)(smem + O_SMAX + (2 * x + half) * 4) = m;
    __syncthreads();
    m = fmaxf(*(const float*)(smem + O_SMAX + 2 * x * 4),
              *(const float*)(smem + O_SMAX + (2 * x + 1) * 4));
    float l = 0.f;
    for (int cc = 0; cc < 8; cc++) {
      int chunk = 8 * half + cc;
      int addr = O_S + x * 256 + (((chunk ^ (x & 7))) << 4);
      h8 sv = *(const h8*)(smem + addr);
      h8 pv;
#pragma unroll
      for (int j = 0; j < 8; j++) {
        float p = __expf((float)sv[j] - m);
        l += p;
        pv[j] = (_Float16)p;
      }
      *(h8*)(smem + addr) = pv;
    }
    *(float*)(smem + O_SSUM + (2 * x + half) * 4) = l;
    __syncthreads();
    if (half == 0) {
      float L = *(const float*)(smem + O_SSUM + 2 * x * 4)
              + *(const float*)(smem + O_SSUM + (2 * x + 1) * 4);
      *(float*)(smem + O_RL + x * 4) = 1.f / L;
    }
  }
  __syncthreads();

  // ---- PV: outT[d][x] = sum_y v[d][y] * P[x][y]  (f16 MFMA, swapped args) ----
  f32x4 acc0 = zero4, acc1 = zero4;
  {
    int X0a = 2 * wv * 16, X0b = X0a + 16;
    for (int ky = 0; ky < 4; ky++) {
      int sw = (((4 * ky + g) ^ (l15 & 7))) << 4;
      h8 vfrag = *(const h8*)(smem + O_VB + l15 * 256 + sw);
      h8 p0 = *(const h8*)(smem + O_S + (X0a + l15) * 256 + sw);
      h8 p1 = *(const h8*)(smem + O_S + (X0b + l15) * 256 + sw);
      acc0 = __builtin_amdgcn_mfma_f32_16x16x32_f16(vfrag, p0, acc0, 0, 0, 0);
      acc1 = __builtin_amdgcn_mfma_f32_16x16x32_f16(vfrag, p1, acc1, 0, 0, 0);
    }
  }
  // ---- PV_enc via skewed P tiles ----
  for (int Ys = 0; Ys < 8; Ys++) {
    int Y0 = Ys * 16;
#pragma unroll
    for (int xi = 0; xi < 2; xi++) {
      int X0 = (2 * wv + xi) * 16;
      int W0 = Y0 - X0 + 112;
      *(f32x4*)(smem + O_SKEW + wv * 1024 + lane * 16) = zero4;  // zero wave scratch
      int xx = l15, x = X0 + xx;
#pragma unroll
      for (int ii = 0; ii < 4; ii++) {
        int yy = 4 * g + ii, y = Y0 + yy;
        u16 pbits = *(const u16*)(smem + O_S + x * 256 + ((((y >> 3) ^ (x & 7))) << 4) + (y & 7) * 2);
        int j = yy - xx + 15;
        *(u16*)(smem + O_SKEW + wv * 1024 + xx * 64 + j * 2) = pbits;
      }
      h8 vefrag = *(const h8*)(smem + O_VEB + l15 * 512 + (((((W0 >> 3) + g) ^ (l15 & 7))) << 4));
      h8 skfrag = *(const h8*)(smem + O_SKEW + wv * 1024 + l15 * 64 + g * 16);
      if (xi == 0) acc0 = __builtin_amdgcn_mfma_f32_16x16x32_f16(vefrag, skfrag, acc0, 0, 0, 0);
      else         acc1 = __builtin_amdgcn_mfma_f32_16x16x32_f16(vefrag, skfrag, acc1, 0, 0, 0);
    }
  }
  // ---- normalize + write otmp[n][c][x] f16 ----
  {
    int X0a = 2 * wv * 16, X0b = X0a + 16;
    float rl0 = *(const float*)(smem + O_RL + (X0a + l15) * 4);
    float rl1 = *(const float*)(smem + O_RL + (X0b + l15) * 4);
    long obase = ((long)(n * 8 + head)) * 2048;
#pragma unroll
    for (int i = 0; i < 4; i++) {
      int d = 4 * g + i;
      otmp[obase + d * 128 + X0a + l15] = (_Float16)(acc0[i] * rl0);
      otmp[obase + d * 128 + X0b + l15] = (_Float16)(acc1[i] * rl1);
    }
  }
}

extern "C" void kernel_launch(void* const* d_in, const int* in_sizes, int n_in,
                              void* d_out, int out_size, void* d_ws, size_t ws_size,
                              hipStream_t stream) {
  const float* x      = (const float*)d_in[0];
  const float* kqv_w  = (const float*)d_in[1];
  const float* kqv_g  = (const float*)d_in[2];
  const float* kqv_b  = (const float*)d_in[3];
  const float* kqv_m  = (const float*)d_in[4];
  const float* kqv_v  = (const float*)d_in[5];
  const float* lg     = (const float*)d_in[6];
  const float* lb     = (const float*)d_in[7];
  const float* lm     = (const float*)d_in[8];
  const float* lv     = (const float*)d_in[9];
  const float* rel    = (const float*)d_in[10];
  float* out = (float*)d_out;

  u16*       xt   = (u16*)d_ws;                               //  8 MiB bf16
  float*     kqv  = (float*)((char*)d_ws + (8u << 20));       // 32 MiB f32
  _Float16*  otmp = (_Float16*)((char*)d_ws + (40u << 20));   //  8.4 MiB f16

  // x (B,C,H,W) f32 -> xt[(b*W+w)][c][h] bf16
  transpose_f2b<<<dim3(4, 4, 256), dim3(32, 8), 0, stream>>>(
      x, xt, 2097152, 16384, 128, 2097152, 128, 16384);
  kqv_gemm<<<dim3(256), dim3(256), 0, stream>>>(
      xt, kqv_w, kqv_g, kqv_b, kqv_m, kqv_v, kqv);
  attn_mfma<<<dim3(8, 256), dim3(256), 0, stream>>>(
      kqv, rel, lg, lb, lm, lv, otmp);
  // otmp[b][w][c][x] f16 -> out[b][c][x][w] f32
  transpose_h2f<<<dim3(4, 4, 256), dim3(32, 8), 0, stream>>>(
      (const u16*)otmp, out, 2097152, 128, 16384, 2097152, 16384, 128);
}

// Round 4
// 114.431 us; speedup vs baseline: 2.0192x; 1.6056x over previous
//
#include <hip/hip_runtime.h>

typedef unsigned short u16;
typedef __attribute__((ext_vector_type(8))) unsigned short u16x8;
typedef __attribute__((ext_vector_type(8))) short s8v;     // 8 bf16 (MFMA A/B frag)
typedef _Float16 h8 __attribute__((ext_vector_type(8)));   // 8 f16  (MFMA A/B frag)
typedef _Float16 h4 __attribute__((ext_vector_type(4)));
typedef __attribute__((ext_vector_type(4))) float f32x4;

__device__ __forceinline__ float b2f(u16 v) {
  union { unsigned int u; float f; } c; c.u = ((unsigned int)v) << 16; return c.f;
}
__device__ __forceinline__ u16 f2b(float f) {
  union { unsigned int u; float f; } c; c.f = f;
  unsigned int u = c.u;
  u += 0x7FFFu + ((u >> 16) & 1u);
  return (u16)(u >> 16);
}

// ---------------- prep: w -> f16 hi/lo planes; rel -> bf16 hi/lo B-tables + f16 Ve ----------------
// relT layout (bytes): eqhi[256][16] @0, eqlo @4096, ekhi @8192, eklo @12288, veb[16][256]f16 @16384
__global__ __launch_bounds__(256) void prep_tables(
    const float* __restrict__ wmat, const float* __restrict__ rel,
    char* __restrict__ whi, char* __restrict__ wlo, char* __restrict__ relT) {
  int tid = threadIdx.x;
  for (int i = tid; i < 32768; i += 256) {
    float v = wmat[i];
    _Float16 h = (_Float16)v;
    ((_Float16*)whi)[i] = h;
    ((_Float16*)wlo)[i] = (_Float16)(v - (float)h);
  }
  int r = tid;  // 0..255 (row 255 = zero pad)
  u16x8 qh, ql, kh, kl;
#pragma unroll
  for (int d = 0; d < 8; d++) {
    float vq = (r < 255) ? rel[d * 255 + r] : 0.f;
    u16 hb = f2b(vq); qh[d] = hb; ql[d] = f2b(vq - b2f(hb));
    float vk = (r < 255) ? rel[(8 + d) * 255 + r] : 0.f;
    hb = f2b(vk); kh[d] = hb; kl[d] = f2b(vk - b2f(hb));
  }
  ((u16x8*)(relT + 0))[r] = qh;
  ((u16x8*)(relT + 4096))[r] = ql;
  ((u16x8*)(relT + 8192))[r] = kh;
  ((u16x8*)(relT + 12288))[r] = kl;
#pragma unroll
  for (int d = 0; d < 16; d++) {
    float vv = (r < 255) ? rel[(16 + d) * 255 + r] : 0.f;
    *(_Float16*)(relT + 16384 + d * 512 + r * 2) = (_Float16)vv;
  }
}

// ---------------- transpose x (B,C,H,W) f32 -> xt2[n=b*128+w][h][c] f16, chunk-swizzled rows ------
__global__ __launch_bounds__(256) void transpose_x(
    const float* __restrict__ x, char* __restrict__ xt2) {
  __shared__ _Float16 tile[32][33];
  int z = blockIdx.z, b = z >> 7, h = z & 127;
  const float* s = x + (size_t)b * 2097152 + h * 128;  // element (c,w): + c*16384 + w
  int tx = threadIdx.x, ty = threadIdx.y;
  int c0 = blockIdx.y * 32, w0 = blockIdx.x * 32;
#pragma unroll
  for (int k = 0; k < 4; k++)
    tile[ty + k * 8][tx] = (_Float16)s[(size_t)(c0 + ty + k * 8) * 16384 + w0 + tx];
  __syncthreads();
#pragma unroll
  for (int k = 0; k < 4; k++) {
    int w = w0 + ty + k * 8;
    int n = b * 128 + w;
    int c = c0 + tx;
    *(_Float16*)(xt2 + (size_t)n * 32768 + h * 256 + ((((c >> 3) ^ (h & 7))) << 4) + (c & 7) * 2) =
        tile[tx][ty + k * 8];
  }
}

// ---------------- kqv MFMA GEMM + BN + preformat emission ----------------
// out per (n,head): qkT planes (Khi,Klo,Qhi,Qlo)[128 x][8 d] bf16; vT [16 d][128 x] f16
#define KQ_XS 0
#define KQ_FMT 16384
#define KQ_INV 33792
#define KQ_BIA 34816
#define LDS_K 35840
__global__ __launch_bounds__(256, 2) void kqv_mfma(
    const char* __restrict__ xt2, const char* __restrict__ whi, const char* __restrict__ wlo,
    const float* __restrict__ gam, const float* __restrict__ bet,
    const float* __restrict__ mea, const float* __restrict__ var,
    char* __restrict__ qkT, char* __restrict__ vT) {
  __shared__ __attribute__((aligned(16))) char sm[LDS_K];
  int tid = threadIdx.x;
  int h0 = 64 * blockIdx.x, n = blockIdx.y;
  int lane = tid & 63, wv = tid >> 6, g = lane >> 4, l15 = lane & 15;
  const char* src = xt2 + (size_t)n * 32768 + h0 * 256;
  for (int i = tid; i < 1024; i += 256)
    ((f32x4*)(sm + KQ_XS))[i] = ((const f32x4*)src)[i];
  {
    float gv = gam[tid], bb = bet[tid], mm = mea[tid], vv = var[tid];
    float inv = gv * rsqrtf(vv + 1e-5f);
    ((float*)(sm + KQ_INV))[tid] = inv;
    ((float*)(sm + KQ_BIA))[tid] = bb - mm * inv;
  }
  __syncthreads();
  f32x4 acc[4][4];
#pragma unroll
  for (int a = 0; a < 4; a++)
#pragma unroll
    for (int b = 0; b < 4; b++) acc[a][b] = (f32x4){0.f, 0.f, 0.f, 0.f};
  const char* wsel = (g & 1) ? wlo : whi;
  int cofs = (g >> 1) * 8;
#pragma unroll
  for (int kk = 0; kk < 8; kk++) {
    h8 af[4], bf[4];
#pragma unroll
    for (int tt = 0; tt < 4; tt++)
      af[tt] = *(const h8*)(wsel + (64 * wv + 16 * tt + l15) * 256 + (16 * kk + cofs) * 2);
#pragma unroll
    for (int ht = 0; ht < 4; ht++)
      bf[ht] = *(const h8*)(sm + KQ_XS + (16 * ht + l15) * 256 +
                            (((2 * kk + (g >> 1)) ^ (l15 & 7)) << 4));
#pragma unroll
    for (int tt = 0; tt < 4; tt++)
#pragma unroll
      for (int ht = 0; ht < 4; ht++)
        acc[tt][ht] = __builtin_amdgcn_mfma_f32_16x16x32_f16(af[tt], bf[ht], acc[tt][ht], 0, 0, 0);
  }
  for (int r = 0; r < 4; r++) {
    if (wv == r) {
#pragma unroll
      for (int tt = 0; tt < 4; tt++)
#pragma unroll
        for (int ht = 0; ht < 4; ht++) {
          int ob = 16 * tt + 4 * g;
#pragma unroll
          for (int i = 0; i < 4; i++) {
            int o = 64 * r + ob + i;
            float inv = ((float*)(sm + KQ_INV))[o];
            float bia = ((float*)(sm + KQ_BIA))[o];
            ((float*)(sm + KQ_FMT))[(ob + i) * 68 + 16 * ht + l15] = acc[tt][ht][i] * inv + bia;
          }
        }
    }
    __syncthreads();
    {  // QK planes
      int xl = tid & 63, hsel = (tid >> 6) & 1, kq = tid >> 7;
      int head = 2 * r + hsel;
      int obl = hsel * 32 + kq * 8;
      u16x8 hi8, lo8;
#pragma unroll
      for (int d = 0; d < 8; d++) {
        float v = ((float*)(sm + KQ_FMT))[(obl + d) * 68 + xl];
        u16 hb = f2b(v);
        hi8[d] = hb;
        lo8[d] = f2b(v - b2f(hb));
      }
      char* dsth = qkT + (size_t)(n * 8 + head) * 8192 + (kq * 2) * 2048 + (h0 + xl) * 16;
      *(u16x8*)dsth = hi8;
      *(u16x8*)(dsth + 2048) = lo8;
    }
    {  // V
      int hsel = tid >> 7, d = (tid >> 3) & 15, xo = tid & 7;
      int head = 2 * r + hsel;
      h8 vv;
#pragma unroll
      for (int j = 0; j < 8; j++)
        vv[j] = (_Float16)((float*)(sm + KQ_FMT))[(hsel * 32 + 16 + d) * 68 + xo * 8 + j];
      *(h8*)(vT + (size_t)(n * 8 + head) * 4096 + d * 256 + (h0 + xo * 8) * 2) = vv;
    }
    __syncthreads();
  }
}

// ---------------- attention: 2 barriers, all-b128 LDS, frags from global ----------------
#define O_S 0
#define S_STRIDE 272
#define O_RS 34816
#define RSBUF 5120
#define LDS_A 75776
__global__ __launch_bounds__(256, 2) void attn_mfma2(
    const char* __restrict__ qkT, const char* __restrict__ vT, const char* __restrict__ relT,
    const float* __restrict__ lg, const float* __restrict__ lb,
    const float* __restrict__ lm, const float* __restrict__ lv,
    _Float16* __restrict__ otmp) {
  __shared__ __attribute__((aligned(16))) char sm[LDS_A];
  const int tid = threadIdx.x;
  const int head = blockIdx.x, n = blockIdx.y;
  const int lane = tid & 63, wv = tid >> 6;
  const int g = lane >> 4, l15 = lane & 15;
  const char* qkb = qkT + (size_t)(n * 8 + head) * 8192;
  const char* vb = vT + (size_t)(n * 8 + head) * 4096;
  const char* eqB = relT + ((g >> 1) ? 4096 : 0);
  const char* ekB = relT + 8192 + ((g >> 1) ? 4096 : 0);
  const char* veB = relT + 16384;
  const char* qA = qkb + 4096 + ((g & 1) ? 2048 : 0);
  const char* kA = qkb + ((g & 1) ? 2048 : 0);
  const char* kB = qkb + ((g >> 1) ? 2048 : 0);

  float a0 = lg[head] * rsqrtf(lv[head] + 1e-5f);
  float a1 = lg[8 + head] * rsqrtf(lv[8 + head] + 1e-5f);
  float a2 = lg[16 + head] * rsqrtf(lv[16 + head] + 1e-5f);
  float bsum = (lb[head] - lm[head] * a0) + (lb[8 + head] - lm[8 + head] * a1) +
               (lb[16 + head] - lm[16 + head] * a2);

  const f32x4 zero4 = {0.f, 0.f, 0.f, 0.f};
  const int X0a = 32 * wv, X0b = X0a + 16;
  s8v qfA = *(const s8v*)(qA + (X0a + l15) * 16);
  s8v qfB = *(const s8v*)(qA + (X0b + l15) * 16);

  // ---- S0: S = a0*(q.k) + bsum (rows 32wv..+31, wave-local) ----
#pragma unroll
  for (int yt = 0; yt < 8; yt++) {
    s8v kb = *(const s8v*)(kB + (yt * 16 + l15) * 16);
    f32x4 d0 = __builtin_amdgcn_mfma_f32_16x16x32_bf16(qfA, kb, zero4, 0, 0, 0);
    f32x4 d1 = __builtin_amdgcn_mfma_f32_16x16x32_bf16(qfB, kb, zero4, 0, 0, 0);
    int y = yt * 16 + l15;
#pragma unroll
    for (int i = 0; i < 4; i++) {
      *(_Float16*)(sm + O_S + (X0a + 4 * g + i) * S_STRIDE + y * 2) = (_Float16)(a0 * d0[i] + bsum);
      *(_Float16*)(sm + O_S + (X0b + 4 * g + i) * S_STRIDE + y * 2) = (_Float16)(a0 * d1[i] + bsum);
    }
  }
  // ---- R1: strips 2wv, 2wv+1 (wave-local scratch, shifted cols -> aligned b128 fixup) ----
#pragma unroll
  for (int st2 = 0; st2 < 2; st2++) {
    int X0 = X0a + 16 * st2;
    s8v af = st2 ? qfB : qfA;
    int rb = 112 - X0;
    char* buf = sm + O_RS + (2 * wv + st2) * RSBUF;
#pragma unroll
    for (int k = 0; k < 9; k++) {
      s8v eb = *(const s8v*)(eqB + (rb + 16 * k + l15) * 16);
      f32x4 d = __builtin_amdgcn_mfma_f32_16x16x32_bf16(af, eb, zero4, 0, 0, 0);
#pragma unroll
      for (int i = 0; i < 4; i++) {
        int xx = 4 * g + i;
        *(_Float16*)(buf + xx * 320 + (16 * k + l15 + xx + 1) * 2) = (_Float16)d[i];
      }
    }
#pragma unroll
    for (int it = 0; it < 4; it++) {
      int xx = 4 * it + g, oct = l15;
      h8 rs = *(const h8*)(buf + xx * 320 + (8 * oct + 16) * 2);
      _Float16* sp = (_Float16*)(sm + O_S + (X0 + xx) * S_STRIDE + oct * 16);
      h8 sv = *(const h8*)sp;
#pragma unroll
      for (int j = 0; j < 8; j++) sv[j] = (_Float16)((float)sv[j] + a1 * (float)rs[j]);
      *(h8*)sp = sv;
    }
  }
  // ---- R2 MFMA: strips 2wv, 2wv+1 -> anti-diagonal store RS2t[s=r_local+yy][yy] ----
#pragma unroll
  for (int st2 = 0; st2 < 2; st2++) {
    int Ys = 2 * wv + st2, Y0 = 16 * Ys, rb2 = 112 - Y0;
    s8v kaf = *(const s8v*)(kA + (Y0 + l15) * 16);
    char* buf = sm + O_RS + Ys * RSBUF;
#pragma unroll
    for (int k = 0; k < 9; k++) {
      s8v eb = *(const s8v*)(ekB + (rb2 + 16 * k + l15) * 16);
      f32x4 d = __builtin_amdgcn_mfma_f32_16x16x32_bf16(kaf, eb, zero4, 0, 0, 0);
#pragma unroll
      for (int i = 0; i < 4; i++) {
        int yy = 4 * g + i;
        *(_Float16*)(buf + (16 * k + l15 + yy) * 32 + yy * 2) = (_Float16)d[i];
      }
    }
  }
  __syncthreads();  // barrier 1: RS2t visible
  // ---- R2 fixup: own rows x strips, contiguous reads [s=x+15][yy] ----
#pragma unroll
  for (int it = 0; it < 4; it++) {
    int xr = 32 * wv + 8 * it + (lane >> 3);
    int strip = lane & 7;
    const char* buf = sm + O_RS + strip * RSBUF + (xr + 15) * 32;
    h8 rs0 = *(const h8*)buf;
    h8 rs1 = *(const h8*)(buf + 16);
    _Float16* sp = (_Float16*)(sm + O_S + xr * S_STRIDE + strip * 32);
    h8 s0 = *(const h8*)sp;
    h8 s1 = *(const h8*)(sp + 8);
#pragma unroll
    for (int j = 0; j < 8; j++) {
      s0[j] = (_Float16)((float)s0[j] + a2 * (float)rs0[j]);
      s1[j] = (_Float16)((float)s1[j] + a2 * (float)rs1[j]);
    }
    *(h8*)sp = s0;
    *(h8*)(sp + 8) = s1;
  }
  __syncthreads();  // barrier 2: fixups done; RS free for skew reuse
  // ---- softmax: row = 32wv + (lane&31), shfl-reduced, P in place ----
  float rl;
  {
    int row = 32 * wv + (lane & 31), half = lane >> 5;
    char* rowp = sm + O_S + row * S_STRIDE + half * 128;
    h8 sv[8];
#pragma unroll
    for (int c = 0; c < 8; c++) sv[c] = *(const h8*)(rowp + c * 16);
    float mrow = -1e30f;
#pragma unroll
    for (int c = 0; c < 8; c++)
#pragma unroll
      for (int j = 0; j < 8; j++) mrow = fmaxf(mrow, (float)sv[c][j]);
    mrow = fmaxf(mrow, __shfl_xor(mrow, 32));
    float lsum = 0.f;
#pragma unroll
    for (int c = 0; c < 8; c++) {
#pragma unroll
      for (int j = 0; j < 8; j++) {
        float p = __expf((float)sv[c][j] - mrow);
        lsum += p;
        sv[c][j] = (_Float16)p;
      }
      *(h8*)(rowp + c * 16) = sv[c];
    }
    lsum += __shfl_xor(lsum, 32);
    rl = 1.f / lsum;
  }
  float rl0 = __shfl(rl, l15);
  float rl1 = __shfl(rl, l15 + 16);
  // ---- PV standard ----
  f32x4 acc0 = zero4, acc1 = zero4;
#pragma unroll
  for (int ky = 0; ky < 4; ky++) {
    int ch = 4 * ky + g;
    h8 vf = *(const h8*)(vb + l15 * 256 + ch * 16);
    h8 p0 = *(const h8*)(sm + O_S + (X0a + l15) * S_STRIDE + ch * 16);
    h8 p1 = *(const h8*)(sm + O_S + (X0b + l15) * S_STRIDE + ch * 16);
    acc0 = __builtin_amdgcn_mfma_f32_16x16x32_f16(vf, p0, acc0, 0, 0, 0);
    acc1 = __builtin_amdgcn_mfma_f32_16x16x32_f16(vf, p1, acc1, 0, 0, 0);
  }
  // ---- PVenc: skewed P tiles, wave-private scratch (zero once; fixed window per row) ----
  char* skb0 = sm + O_RS + (2 * wv) * RSBUF;
  char* skb1 = skb0 + RSBUF;
  *(f32x4*)(skb0 + lane * 16) = zero4;
  *(f32x4*)(skb1 + lane * 16) = zero4;
  for (int Ys = 0; Ys < 8; Ys++) {
    int Y0 = 16 * Ys;
#pragma unroll
    for (int xi = 0; xi < 2; xi++) {
      int X0 = xi ? X0b : X0a;
      char* skb = xi ? skb1 : skb0;
      int W0 = Y0 - X0 + 112;
      h4 pv = *(const h4*)(sm + O_S + (X0 + l15) * S_STRIDE + (Y0 + 4 * g) * 2);
#pragma unroll
      for (int jj = 0; jj < 4; jj++) {
        int j = 4 * g + jj - l15 + 15;
        *(_Float16*)(skb + l15 * 64 + j * 2) = pv[jj];
      }
      h8 vef = *(const h8*)(veB + l15 * 512 + (W0 + 8 * g) * 2);
      h8 skf = *(const h8*)(skb + l15 * 64 + g * 16);
      if (xi == 0) acc0 = __builtin_amdgcn_mfma_f32_16x16x32_f16(vef, skf, acc0, 0, 0, 0);
      else         acc1 = __builtin_amdgcn_mfma_f32_16x16x32_f16(vef, skf, acc1, 0, 0, 0);
    }
  }
  // ---- normalize + write otmp[n][c][x] f16 ----
  size_t obase = (size_t)(n * 8 + head) * 2048;
#pragma unroll
  for (int i = 0; i < 4; i++) {
    int d = 4 * g + i;
    otmp[obase + d * 128 + X0a + l15] = (_Float16)(acc0[i] * rl0);
    otmp[obase + d * 128 + X0b + l15] = (_Float16)(acc1[i] * rl1);
  }
}

// ---------------- otmp f16 -> out f32 transpose (proven in R3) ----------------
__global__ __launch_bounds__(256) void transpose_h2f(
    const u16* __restrict__ src, float* __restrict__ dst,
    int sb, int sc, int sstr, int db, int dc, int dstr) {
  __shared__ u16 tile[32][33];
  int z = blockIdx.z, b = z >> 7, c = z & 127;
  const u16* s = src + (size_t)b * sb + c * sc;
  float* d = dst + (size_t)b * db + c * dc;
  int tx = threadIdx.x, ty = threadIdx.y;
  int r0 = blockIdx.y * 32, c0 = blockIdx.x * 32;
#pragma unroll
  for (int k = 0; k < 4; k++)
    tile[ty + k * 8][tx] = s[(size_t)(r0 + ty + k * 8) * sstr + c0 + tx];
  __syncthreads();
#pragma unroll
  for (int k = 0; k < 4; k++) {
    u16 hv = tile[tx][ty + k * 8];
    d[(size_t)(c0 + ty + k * 8) * dstr + r0 + tx] = (float)(*(const _Float16*)&hv);
  }
}

extern "C" void kernel_launch(void* const* d_in, const int* in_sizes, int n_in,
                              void* d_out, int out_size, void* d_ws, size_t ws_size,
                              hipStream_t stream) {
  const float* x     = (const float*)d_in[0];
  const float* kqv_w = (const float*)d_in[1];
  const float* kqv_g = (const float*)d_in[2];
  const float* kqv_b = (const float*)d_in[3];
  const float* kqv_m = (const float*)d_in[4];
  const float* kqv_v = (const float*)d_in[5];
  const float* lg    = (const float*)d_in[6];
  const float* lb    = (const float*)d_in[7];
  const float* lm    = (const float*)d_in[8];
  const float* lv    = (const float*)d_in[9];
  const float* rel   = (const float*)d_in[10];
  float* out = (float*)d_out;

  char* ws = (char*)d_ws;
  char* xt2  = ws;                        //  8 MiB f16 swizzled [n][h][c]
  char* qkT  = ws + 8388608;              // 16 MiB bf16 hi/lo planes
  char* vT   = ws + 25165824;             //  8 MiB f16 [n,h][d][x]
  _Float16* otmp = (_Float16*)(ws + 33554432);  // 8 MiB f16
  char* whi  = ws + 41943040;             // 64 KiB
  char* wlo  = ws + 42008576;             // 64 KiB
  char* relT = ws + 42074112;             // 24 KiB

  prep_tables<<<1, 256, 0, stream>>>(kqv_w, rel, whi, wlo, relT);
  transpose_x<<<dim3(4, 4, 256), dim3(32, 8), 0, stream>>>(x, xt2);
  kqv_mfma<<<dim3(2, 256), 256, 0, stream>>>(xt2, whi, wlo, kqv_g, kqv_b, kqv_m, kqv_v, qkT, vT);
  attn_mfma2<<<dim3(8, 256), 256, 0, stream>>>(qkT, vT, relT, lg, lb, lm, lv, otmp);
  transpose_h2f<<<dim3(4, 4, 256), dim3(32, 8), 0, stream>>>(
      (const u16*)otmp, out, 2097152, 128, 16384, 2097152, 16384, 128);
}

// Round 5
// 85.536 us; speedup vs baseline: 2.7012x; 1.3378x over previous
//
#include <hip/hip_runtime.h>

typedef unsigned short u16;
typedef unsigned int u32;
typedef __attribute__((ext_vector_type(8))) unsigned short u16x8;
typedef __attribute__((ext_vector_type(8))) short s8v;     // 8 bf16 (MFMA A/B frag)
typedef _Float16 h8 __attribute__((ext_vector_type(8)));   // 8 f16  (MFMA A/B frag)
typedef _Float16 h4 __attribute__((ext_vector_type(4)));
typedef __attribute__((ext_vector_type(4))) float f32x4;

__device__ __forceinline__ float b2f(u16 v) {
  union { unsigned int u; float f; } c; c.u = ((unsigned int)v) << 16; return c.f;
}
__device__ __forceinline__ u16 f2b(float f) {
  union { unsigned int u; float f; } c; c.f = f;
  unsigned int u = c.u;
  u += 0x7FFFu + ((u >> 16) & 1u);
  return (u16)(u >> 16);
}
__device__ __forceinline__ u32 packh2(float a, float b) {
  union { _Float16 h; u16 u; } ca, cb; ca.h = (_Float16)a; cb.h = (_Float16)b;
  return (u32)ca.u | ((u32)cb.u << 16);
}

// ---------------- prep (now 33 blocks): w -> f16 hi/lo; rel -> bf16 hi/lo + f16 Ve ---------
// relT: eqhi[256][16B] @0, eqlo @4096, ekhi @8192, eklo @12288, veb[16][256]f16 @16384
__global__ __launch_bounds__(256) void prep_tables(
    const float* __restrict__ wmat, const float* __restrict__ rel,
    char* __restrict__ whi, char* __restrict__ wlo, char* __restrict__ relT) {
  int tid = threadIdx.x, blk = blockIdx.x;
  if (blk < 32) {
    int i = blk * 1024 + tid;
#pragma unroll
    for (int k = 0; k < 4; k++, i += 256) {
      float v = wmat[i];
      _Float16 h = (_Float16)v;
      ((_Float16*)whi)[i] = h;
      ((_Float16*)wlo)[i] = (_Float16)(v - (float)h);
    }
    return;
  }
  int r = tid;  // 0..255 (255 = zero pad)
  u16x8 qh, ql, kh, kl;
#pragma unroll
  for (int d = 0; d < 8; d++) {
    float vq = (r < 255) ? rel[d * 255 + r] : 0.f;
    u16 hb = f2b(vq); qh[d] = hb; ql[d] = f2b(vq - b2f(hb));
    float vk = (r < 255) ? rel[(8 + d) * 255 + r] : 0.f;
    hb = f2b(vk); kh[d] = hb; kl[d] = f2b(vk - b2f(hb));
  }
  ((u16x8*)(relT + 0))[r] = qh;
  ((u16x8*)(relT + 4096))[r] = ql;
  ((u16x8*)(relT + 8192))[r] = kh;
  ((u16x8*)(relT + 12288))[r] = kl;
#pragma unroll
  for (int d = 0; d < 16; d++) {
    float vv = (r < 255) ? rel[(16 + d) * 255 + r] : 0.f;
    *(_Float16*)(relT + 16384 + d * 512 + r * 2) = (_Float16)vv;
  }
}

// ---------------- transpose x (B,C,H,W) f32 -> xt2[n][h][c] f16 swizzled ----------------
__global__ __launch_bounds__(256) void transpose_x(
    const float* __restrict__ x, char* __restrict__ xt2) {
  __shared__ _Float16 tile[32][33];
  int z = blockIdx.z, b = z >> 7, h = z & 127;
  const float* s = x + (size_t)b * 2097152 + h * 128;
  int tx = threadIdx.x, ty = threadIdx.y;
  int c0 = blockIdx.y * 32, w0 = blockIdx.x * 32;
#pragma unroll
  for (int k = 0; k < 4; k++)
    tile[ty + k * 8][tx] = (_Float16)s[(size_t)(c0 + ty + k * 8) * 16384 + w0 + tx];
  __syncthreads();
#pragma unroll
  for (int k = 0; k < 4; k++) {
    int w = w0 + ty + k * 8;
    int n = b * 128 + w;
    int c = c0 + tx;
    *(_Float16*)(xt2 + (size_t)n * 32768 + h * 256 + ((((c >> 3) ^ (h & 7))) << 4) + (c & 7) * 2) =
        tile[tx][ty + k * 8];
  }
}

// ---------------- kqv MFMA GEMM + BN + preformat emission (unchanged from R4) ----------------
#define KQ_XS 0
#define KQ_FMT 16384
#define KQ_INV 33792
#define KQ_BIA 34816
#define LDS_K 35840
__global__ __launch_bounds__(256, 2) void kqv_mfma(
    const char* __restrict__ xt2, const char* __restrict__ whi, const char* __restrict__ wlo,
    const float* __restrict__ gam, const float* __restrict__ bet,
    const float* __restrict__ mea, const float* __restrict__ var,
    char* __restrict__ qkT, char* __restrict__ vT) {
  __shared__ __attribute__((aligned(16))) char sm[LDS_K];
  int tid = threadIdx.x;
  int h0 = 64 * blockIdx.x, n = blockIdx.y;
  int lane = tid & 63, wv = tid >> 6, g = lane >> 4, l15 = lane & 15;
  const char* src = xt2 + (size_t)n * 32768 + h0 * 256;
  for (int i = tid; i < 1024; i += 256)
    ((f32x4*)(sm + KQ_XS))[i] = ((const f32x4*)src)[i];
  {
    float gv = gam[tid], bb = bet[tid], mm = mea[tid], vv = var[tid];
    float inv = gv * rsqrtf(vv + 1e-5f);
    ((float*)(sm + KQ_INV))[tid] = inv;
    ((float*)(sm + KQ_BIA))[tid] = bb - mm * inv;
  }
  __syncthreads();
  f32x4 acc[4][4];
#pragma unroll
  for (int a = 0; a < 4; a++)
#pragma unroll
    for (int b = 0; b < 4; b++) acc[a][b] = (f32x4){0.f, 0.f, 0.f, 0.f};
  const char* wsel = (g & 1) ? wlo : whi;
  int cofs = (g >> 1) * 8;
#pragma unroll
  for (int kk = 0; kk < 8; kk++) {
    h8 af[4], bf[4];
#pragma unroll
    for (int tt = 0; tt < 4; tt++)
      af[tt] = *(const h8*)(wsel + (64 * wv + 16 * tt + l15) * 256 + (16 * kk + cofs) * 2);
#pragma unroll
    for (int ht = 0; ht < 4; ht++)
      bf[ht] = *(const h8*)(sm + KQ_XS + (16 * ht + l15) * 256 +
                            (((2 * kk + (g >> 1)) ^ (l15 & 7)) << 4));
#pragma unroll
    for (int tt = 0; tt < 4; tt++)
#pragma unroll
      for (int ht = 0; ht < 4; ht++)
        acc[tt][ht] = __builtin_amdgcn_mfma_f32_16x16x32_f16(af[tt], bf[ht], acc[tt][ht], 0, 0, 0);
  }
  for (int r = 0; r < 4; r++) {
    if (wv == r) {
#pragma unroll
      for (int tt = 0; tt < 4; tt++)
#pragma unroll
        for (int ht = 0; ht < 4; ht++) {
          int ob = 16 * tt + 4 * g;
#pragma unroll
          for (int i = 0; i < 4; i++) {
            int o = 64 * r + ob + i;
            float inv = ((float*)(sm + KQ_INV))[o];
            float bia = ((float*)(sm + KQ_BIA))[o];
            ((float*)(sm + KQ_FMT))[(ob + i) * 68 + 16 * ht + l15] = acc[tt][ht][i] * inv + bia;
          }
        }
    }
    __syncthreads();
    {  // QK planes: Khi@0, Klo@2048, Qhi@4096, Qlo@6144 per (n,head)
      int xl = tid & 63, hsel = (tid >> 6) & 1, kq = tid >> 7;
      int headi = 2 * r + hsel;
      int obl = hsel * 32 + kq * 8;
      u16x8 hi8, lo8;
#pragma unroll
      for (int d = 0; d < 8; d++) {
        float v = ((float*)(sm + KQ_FMT))[(obl + d) * 68 + xl];
        u16 hb = f2b(v);
        hi8[d] = hb;
        lo8[d] = f2b(v - b2f(hb));
      }
      char* dsth = qkT + (size_t)(n * 8 + headi) * 8192 + (kq * 2) * 2048 + (h0 + xl) * 16;
      *(u16x8*)dsth = hi8;
      *(u16x8*)(dsth + 2048) = lo8;
    }
    {  // V: [16 d][128 x] f16
      int hsel = tid >> 7, d = (tid >> 3) & 15, xo = tid & 7;
      int headi = 2 * r + hsel;
      h8 vv;
#pragma unroll
      for (int j = 0; j < 8; j++)
        vv[j] = (_Float16)((float*)(sm + KQ_FMT))[(hsel * 32 + 16 + d) * 68 + xo * 8 + j];
      *(h8*)(vT + (size_t)(n * 8 + headi) * 4096 + d * 256 + (h0 + xo * 8) * 2) = vv;
    }
    __syncthreads();
  }
}

// ---------------- attention v3: S in registers, 1 barrier ----------------
// LDS: bufT1 f32 [wave][16 x][148 dw] @0 (skew scratch aliased post-barrier);
//      bufT2 f16 [8 strip][16 y][148 h] @37888
#define T1_STRIDE 592
#define T1_WAVE   9472
#define O_T2      37888
#define T2_STRIDE 296
#define T2_STRIP  4736
#define LDS_A     75776
__global__ __launch_bounds__(256, 2) void attn_mfma3(
    const char* __restrict__ qkT, const char* __restrict__ vT, const char* __restrict__ relT,
    const float* __restrict__ lg, const float* __restrict__ lb,
    const float* __restrict__ lm, const float* __restrict__ lv,
    _Float16* __restrict__ otmp) {
  __shared__ __attribute__((aligned(16))) char sm[LDS_A];
  const int tid = threadIdx.x;
  const int head = blockIdx.x, n = blockIdx.y;
  const int lane = tid & 63, wv = tid >> 6;
  const int g = lane >> 4, l15 = lane & 15;
  const char* qkb = qkT + (size_t)(n * 8 + head) * 8192;
  const char* vb = vT + (size_t)(n * 8 + head) * 4096;
  // operand-plane bases: A-side hi/lo by (g&1) = (hi,lo,hi,lo); B-side by (g>>1) = (hi,hi,lo,lo)
  const char* kAp = qkb + ((g & 1) ? 2048 : 0);
  const char* qBp = qkb + 4096 + ((g >> 1) ? 2048 : 0);
  const char* kBp = qkb + ((g >> 1) ? 2048 : 0);
  const char* eqA = relT + ((g & 1) ? 4096 : 0);
  const char* ekA = relT + 8192 + ((g & 1) ? 4096 : 0);
  const char* veB = relT + 16384;

  float a0 = lg[head] * rsqrtf(lv[head] + 1e-5f);
  float a1 = lg[8 + head] * rsqrtf(lv[8 + head] + 1e-5f);
  float a2 = lg[16 + head] * rsqrtf(lv[16 + head] + 1e-5f);
  float bsum = (lb[head] - lm[head] * a0) + (lb[8 + head] - lm[8 + head] * a1) +
               (lb[16 + head] - lm[16 + head] * a2);

  const f32x4 zero4 = {0.f, 0.f, 0.f, 0.f};
  const int X0a = 32 * wv, X0b = X0a + 16;
  char* t1 = sm + wv * T1_WAVE;

  // ---- S0: lane holds S[x = X0+l15][y = 16yt+4g+i] (swapped operands: A=k, B=q) ----
  s8v qfA = *(const s8v*)(qBp + (X0a + l15) * 16);
  s8v qfB = *(const s8v*)(qBp + (X0b + l15) * 16);
  f32x4 s0[8], s1[8];
#pragma unroll
  for (int yt = 0; yt < 8; yt++) {
    s8v ka = *(const s8v*)(kAp + (yt * 16 + l15) * 16);
    f32x4 d0 = __builtin_amdgcn_mfma_f32_16x16x32_bf16(ka, qfA, zero4, 0, 0, 0);
    f32x4 d1 = __builtin_amdgcn_mfma_f32_16x16x32_bf16(ka, qfB, zero4, 0, 0, 0);
#pragma unroll
    for (int i = 0; i < 4; i++) {
      s0[yt][i] = a0 * d0[i] + bsum;
      s1[yt][i] = a0 * d1[i] + bsum;
    }
  }

  // ---- R1: Rq[r][x] per x-tile; f32 scratch, transposed (b128 stores, read2-pair reads) ----
  {
    s8v eqf[10];
    int rbu = 96 - X0a;  // union tile base; xt-a uses t+1, xt-b uses t
#pragma unroll
    for (int t = 0; t < 10; t++)
      eqf[t] = *(const s8v*)(eqA + (rbu + 16 * t + l15) * 16);
#pragma unroll
    for (int t = 0; t < 9; t++) {
      f32x4 d = __builtin_amdgcn_mfma_f32_16x16x32_bf16(eqf[t + 1], qfA, zero4, 0, 0, 0);
      *(f32x4*)(t1 + l15 * T1_STRIDE + (16 * t + 4 * g) * 4) = d;
    }
    {
      const float* r1p = (const float*)(t1 + l15 * T1_STRIDE) + (4 * g + 15 - l15);
#pragma unroll
      for (int yt = 0; yt < 8; yt++)
#pragma unroll
        for (int i = 0; i < 4; i++) s0[yt][i] += a1 * r1p[16 * yt + i];
    }
#pragma unroll
    for (int t = 0; t < 9; t++) {
      f32x4 d = __builtin_amdgcn_mfma_f32_16x16x32_bf16(eqf[t], qfB, zero4, 0, 0, 0);
      *(f32x4*)(t1 + l15 * T1_STRIDE + (16 * t + 4 * g) * 4) = d;
    }
    {
      const float* r1p = (const float*)(t1 + l15 * T1_STRIDE) + (4 * g + 15 - l15);
#pragma unroll
      for (int yt = 0; yt < 8; yt++)
#pragma unroll
        for (int i = 0; i < 4; i++) s1[yt][i] += a1 * r1p[16 * yt + i];
    }
  }

  // ---- R2: Rk[r][y] for strips 2wv, 2wv+1 -> f16 scratch (b64 stores) ----
  {
    s8v ekf[10];
    int rbu2 = 96 - 32 * wv;  // strip 2wv uses t+1, strip 2wv+1 uses t
#pragma unroll
    for (int t = 0; t < 10; t++)
      ekf[t] = *(const s8v*)(ekA + (rbu2 + 16 * t + l15) * 16);
#pragma unroll
    for (int st = 0; st < 2; st++) {
      int Ys = 2 * wv + st;
      s8v kf = *(const s8v*)(kBp + (Ys * 16 + l15) * 16);
      char* t2 = sm + O_T2 + Ys * T2_STRIP;
#pragma unroll
      for (int t = 0; t < 9; t++) {
        f32x4 d = __builtin_amdgcn_mfma_f32_16x16x32_bf16(ekf[t + 1 - st], kf, zero4, 0, 0, 0);
        h4 hv;
#pragma unroll
        for (int i = 0; i < 4; i++) hv[i] = (_Float16)d[i];
        *(h4*)(t2 + l15 * T2_STRIDE + (16 * t + 4 * g) * 2) = hv;
      }
    }
  }
  __syncthreads();  // the only barrier: bufT2 visible to all waves

  // ---- R2 merge: r_local = X0 + l15 + 15 - 4g - ir (yt-independent) ----
#pragma unroll
  for (int ir = 0; ir < 4; ir++) {
    const char* b2 = sm + O_T2 + (4 * g + ir) * T2_STRIDE + (X0a + l15 + 15 - 4 * g - ir) * 2;
#pragma unroll
    for (int yt = 0; yt < 8; yt++) {
      float v0 = (float)*(const _Float16*)(b2 + yt * T2_STRIP);
      float v1 = (float)*(const _Float16*)(b2 + yt * T2_STRIP + 32);
      s0[yt][ir] += a2 * v0;
      s1[yt][ir] += a2 * v1;
    }
  }

  // ---- softmax (row x per lane; reduce across g via shfl_xor 16,32) ----
  float rl0, rl1;
  {
    float m0 = -1e30f, m1 = -1e30f;
#pragma unroll
    for (int yt = 0; yt < 8; yt++)
#pragma unroll
      for (int i = 0; i < 4; i++) {
        m0 = fmaxf(m0, s0[yt][i]);
        m1 = fmaxf(m1, s1[yt][i]);
      }
    m0 = fmaxf(m0, __shfl_xor(m0, 16)); m0 = fmaxf(m0, __shfl_xor(m0, 32));
    m1 = fmaxf(m1, __shfl_xor(m1, 16)); m1 = fmaxf(m1, __shfl_xor(m1, 32));
    float l0 = 0.f, l1 = 0.f;
#pragma unroll
    for (int yt = 0; yt < 8; yt++)
#pragma unroll
      for (int i = 0; i < 4; i++) {
        float p0 = __expf(s0[yt][i] - m0); s0[yt][i] = p0; l0 += p0;
        float p1 = __expf(s1[yt][i] - m1); s1[yt][i] = p1; l1 += p1;
      }
    l0 += __shfl_xor(l0, 16); l0 += __shfl_xor(l0, 32);
    l1 += __shfl_xor(l1, 16); l1 += __shfl_xor(l1, 32);
    rl0 = 1.f / l0; rl1 = 1.f / l1;
  }

  // ---- pack P to f16 pairs ----
  u32 ppk0[8][2], ppk1[8][2];
#pragma unroll
  for (int yt = 0; yt < 8; yt++) {
    ppk0[yt][0] = packh2(s0[yt][0], s0[yt][1]);
    ppk0[yt][1] = packh2(s0[yt][2], s0[yt][3]);
    ppk1[yt][0] = packh2(s1[yt][0], s1[yt][1]);
    ppk1[yt][1] = packh2(s1[yt][2], s1[yt][3]);
  }

  // ---- PV: B-frag via ds_bpermute (pull both yt-candidates, dest-select) ----
  f32x4 acc0 = zero4, acc1 = zero4;
  {
    int addrA = ((2 * (g & 1)) * 16 + l15) * 4;
    int addrB = addrA + 64;
    bool hi = (g >> 1) != 0;
#pragma unroll
    for (int ky = 0; ky < 4; ky++) {
      h8 vf = *(const h8*)(vb + l15 * 256 + (32 * ky + 8 * g) * 2);
      union { u32 w[4]; h8 v; } pa, pb;
#pragma unroll
      for (int p = 0; p < 2; p++) {
        u32 e0a = __builtin_amdgcn_ds_bpermute(addrA, (int)ppk0[2 * ky][p]);
        u32 e1a = __builtin_amdgcn_ds_bpermute(addrA, (int)ppk0[2 * ky + 1][p]);
        u32 e0b = __builtin_amdgcn_ds_bpermute(addrB, (int)ppk0[2 * ky][p]);
        u32 e1b = __builtin_amdgcn_ds_bpermute(addrB, (int)ppk0[2 * ky + 1][p]);
        pa.w[p] = hi ? e1a : e0a;
        pa.w[p + 2] = hi ? e1b : e0b;
        u32 f0a = __builtin_amdgcn_ds_bpermute(addrA, (int)ppk1[2 * ky][p]);
        u32 f1a = __builtin_amdgcn_ds_bpermute(addrA, (int)ppk1[2 * ky + 1][p]);
        u32 f0b = __builtin_amdgcn_ds_bpermute(addrB, (int)ppk1[2 * ky][p]);
        u32 f1b = __builtin_amdgcn_ds_bpermute(addrB, (int)ppk1[2 * ky + 1][p]);
        pb.w[p] = hi ? f1a : f0a;
        pb.w[p + 2] = hi ? f1b : f0b;
      }
      acc0 = __builtin_amdgcn_mfma_f32_16x16x32_f16(vf, pa.v, acc0, 0, 0, 0);
      acc1 = __builtin_amdgcn_mfma_f32_16x16x32_f16(vf, pb.v, acc1, 0, 0, 0);
    }
  }

  // ---- PVenc: skew scratch (stride 80) aliased over bufT1; sourced from registers ----
  {
    char* skb0 = t1;           // 16 rows x 80B
    char* skb1 = t1 + 1280;
    for (int i = lane; i < 160; i += 64) *(f32x4*)(t1 + i * 16) = zero4;
    h8 vef[9];
#pragma unroll
    for (int u = 0; u < 9; u++)
      vef[u] = *(const h8*)(veB + l15 * 512 + ((96 - X0a + 16 * u) + 8 * g) * 2);
    int j0 = 4 * g + 15 - l15;
#pragma unroll
    for (int Ys = 0; Ys < 8; Ys++) {
      {
        u32 pk0 = ppk0[Ys][0], pk1 = ppk0[Ys][1];
        char* rp = skb0 + l15 * 80;
        *(u16*)(rp + (j0 + 0) * 2) = (u16)(pk0 & 0xffff);
        *(u16*)(rp + (j0 + 1) * 2) = (u16)(pk0 >> 16);
        *(u16*)(rp + (j0 + 2) * 2) = (u16)(pk1 & 0xffff);
        *(u16*)(rp + (j0 + 3) * 2) = (u16)(pk1 >> 16);
        h8 skf = *(const h8*)(skb0 + l15 * 80 + g * 16);
        acc0 = __builtin_amdgcn_mfma_f32_16x16x32_f16(vef[Ys + 1], skf, acc0, 0, 0, 0);
      }
      {
        u32 pk0 = ppk1[Ys][0], pk1 = ppk1[Ys][1];
        char* rp = skb1 + l15 * 80;
        *(u16*)(rp + (j0 + 0) * 2) = (u16)(pk0 & 0xffff);
        *(u16*)(rp + (j0 + 1) * 2) = (u16)(pk0 >> 16);
        *(u16*)(rp + (j0 + 2) * 2) = (u16)(pk1 & 0xffff);
        *(u16*)(rp + (j0 + 3) * 2) = (u16)(pk1 >> 16);
        h8 skf = *(const h8*)(skb1 + l15 * 80 + g * 16);
        acc1 = __builtin_amdgcn_mfma_f32_16x16x32_f16(vef[Ys], skf, acc1, 0, 0, 0);
      }
    }
  }

  // ---- normalize + write otmp[n][c][x] f16 ----
  size_t obase = (size_t)(n * 8 + head) * 2048;
#pragma unroll
  for (int i = 0; i < 4; i++) {
    int d = 4 * g + i;
    otmp[obase + d * 128 + X0a + l15] = (_Float16)(acc0[i] * rl0);
    otmp[obase + d * 128 + X0b + l15] = (_Float16)(acc1[i] * rl1);
  }
}

// ---------------- otmp f16 -> out f32 transpose ----------------
__global__ __launch_bounds__(256) void transpose_h2f(
    const u16* __restrict__ src, float* __restrict__ dst,
    int sb, int sc, int sstr, int db, int dc, int dstr) {
  __shared__ u16 tile[32][33];
  int z = blockIdx.z, b = z >> 7, c = z & 127;
  const u16* s = src + (size_t)b * sb + c * sc;
  float* d = dst + (size_t)b * db + c * dc;
  int tx = threadIdx.x, ty = threadIdx.y;
  int r0 = blockIdx.y * 32, c0 = blockIdx.x * 32;
#pragma unroll
  for (int k = 0; k < 4; k++)
    tile[ty + k * 8][tx] = s[(size_t)(r0 + ty + k * 8) * sstr + c0 + tx];
  __syncthreads();
#pragma unroll
  for (int k = 0; k < 4; k++) {
    u16 hv = tile[tx][ty + k * 8];
    d[(size_t)(c0 + ty + k * 8) * dstr + r0 + tx] = (float)(*(const _Float16*)&hv);
  }
}

extern "C" void kernel_launch(void* const* d_in, const int* in_sizes, int n_in,
                              void* d_out, int out_size, void* d_ws, size_t ws_size,
                              hipStream_t stream) {
  const float* x     = (const float*)d_in[0];
  const float* kqv_w = (const float*)d_in[1];
  const float* kqv_g = (const float*)d_in[2];
  const float* kqv_b = (const float*)d_in[3];
  const float* kqv_m = (const float*)d_in[4];
  const float* kqv_v = (const float*)d_in[5];
  const float* lg    = (const float*)d_in[6];
  const float* lb    = (const float*)d_in[7];
  const float* lm    = (const float*)d_in[8];
  const float* lv    = (const float*)d_in[9];
  const float* rel   = (const float*)d_in[10];
  float* out = (float*)d_out;

  char* ws = (char*)d_ws;
  char* xt2  = ws;                              //  8 MiB f16 swizzled [n][h][c]
  char* qkT  = ws + 8388608;                    // 16 MiB bf16 hi/lo planes
  char* vT   = ws + 25165824;                   //  8 MiB f16 [n,h][d][x]
  _Float16* otmp = (_Float16*)(ws + 33554432);  //  8 MiB f16
  char* whi  = ws + 41943040;                   // 64 KiB
  char* wlo  = ws + 42008576;                   // 64 KiB
  char* relT = ws + 42074112;                   // 24 KiB

  prep_tables<<<33, 256, 0, stream>>>(kqv_w, rel, whi, wlo, relT);
  transpose_x<<<dim3(4, 4, 256), dim3(32, 8), 0, stream>>>(x, xt2);
  kqv_mfma<<<dim3(2, 256), 256, 0, stream>>>(xt2, whi, wlo, kqv_g, kqv_b, kqv_m, kqv_v, qkT, vT);
  attn_mfma3<<<dim3(8, 256), 256, 0, stream>>>(qkT, vT, relT, lg, lb, lm, lv, otmp);
  transpose_h2f<<<dim3(4, 4, 256), dim3(32, 8), 0, stream>>>(
      (const u16*)otmp, out, 2097152, 128, 16384, 2097152, 16384, 128);
}

// Round 6
// 80.671 us; speedup vs baseline: 2.8641x; 1.0603x over previous
//
#include <hip/hip_runtime.h>

typedef unsigned short u16;
typedef unsigned int u32;
typedef __attribute__((ext_vector_type(8))) unsigned short u16x8;
typedef __attribute__((ext_vector_type(8))) short s8v;     // 8 bf16 (MFMA A/B frag)
typedef _Float16 h8 __attribute__((ext_vector_type(8)));   // 8 f16  (MFMA A/B frag)
typedef _Float16 h4 __attribute__((ext_vector_type(4)));
typedef __attribute__((ext_vector_type(4))) float f32x4;

__device__ __forceinline__ float b2f(u16 v) {
  union { unsigned int u; float f; } c; c.u = ((unsigned int)v) << 16; return c.f;
}
__device__ __forceinline__ u16 f2b(float f) {
  union { unsigned int u; float f; } c; c.f = f;
  unsigned int u = c.u;
  u += 0x7FFFu + ((u >> 16) & 1u);
  return (u16)(u >> 16);
}
__device__ __forceinline__ u32 packh2(float a, float b) {
  union { _Float16 h; u16 u; } ca, cb; ca.h = (_Float16)a; cb.h = (_Float16)b;
  return (u32)ca.u | ((u32)cb.u << 16);
}
__device__ __forceinline__ u16 f2h_bits(float a) {
  union { _Float16 h; u16 u; } c; c.h = (_Float16)a; return c.u;
}

// ---------------- prep: w -> f16 hi/lo; rel -> bf16 hi/lo + f16 Ve (zero-padded) ---------
// relT: eqhi[256][16B] @0, eqlo @4096, ekhi @8192, eklo @12288, veb[16 d][512 h] @16384 (stride 1024B)
__global__ __launch_bounds__(256) void prep_tables(
    const float* __restrict__ wmat, const float* __restrict__ rel,
    char* __restrict__ whi, char* __restrict__ wlo, char* __restrict__ relT) {
  int tid = threadIdx.x, blk = blockIdx.x;
  if (blk < 32) {
    int i = blk * 1024 + tid;
#pragma unroll
    for (int k = 0; k < 4; k++, i += 256) {
      float v = wmat[i];
      _Float16 h = (_Float16)v;
      ((_Float16*)whi)[i] = h;
      ((_Float16*)wlo)[i] = (_Float16)(v - (float)h);
    }
    return;
  }
  int r = tid;  // 0..255 (255 = zero pad)
  u16x8 qh, ql, kh, kl;
#pragma unroll
  for (int d = 0; d < 8; d++) {
    float vq = (r < 255) ? rel[d * 255 + r] : 0.f;
    u16 hb = f2b(vq); qh[d] = hb; ql[d] = f2b(vq - b2f(hb));
    float vk = (r < 255) ? rel[(8 + d) * 255 + r] : 0.f;
    hb = f2b(vk); kh[d] = hb; kl[d] = f2b(vk - b2f(hb));
  }
  ((u16x8*)(relT + 0))[r] = qh;
  ((u16x8*)(relT + 4096))[r] = ql;
  ((u16x8*)(relT + 8192))[r] = kh;
  ((u16x8*)(relT + 12288))[r] = kl;
#pragma unroll
  for (int d = 0; d < 16; d++) {
    float vv = (r < 255) ? rel[(16 + d) * 255 + r] : 0.f;
    *(_Float16*)(relT + 16384 + d * 1024 + r * 2) = (_Float16)vv;
    *(_Float16*)(relT + 16384 + d * 1024 + (256 + r) * 2) = (_Float16)0.f;  // zero overhang
  }
}

// ---------------- transpose x (B,C,H,W) f32 -> xt2[n][h][c] f16 swizzled ----------------
__global__ __launch_bounds__(256) void transpose_x(
    const float* __restrict__ x, char* __restrict__ xt2) {
  __shared__ _Float16 tile[32][33];
  int z = blockIdx.z, b = z >> 7, h = z & 127;
  const float* s = x + (size_t)b * 2097152 + h * 128;
  int tx = threadIdx.x, ty = threadIdx.y;
  int c0 = blockIdx.y * 32, w0 = blockIdx.x * 32;
#pragma unroll
  for (int k = 0; k < 4; k++)
    tile[ty + k * 8][tx] = (_Float16)s[(size_t)(c0 + ty + k * 8) * 16384 + w0 + tx];
  __syncthreads();
#pragma unroll
  for (int k = 0; k < 4; k++) {
    int w = w0 + ty + k * 8;
    int n = b * 128 + w;
    int c = c0 + tx;
    *(_Float16*)(xt2 + (size_t)n * 32768 + h * 256 + ((((c >> 3) ^ (h & 7))) << 4) + (c & 7) * 2) =
        tile[tx][ty + k * 8];
  }
}

// ---------------- kqv MFMA GEMM + BN + preformat emission (unchanged) ----------------
#define KQ_XS 0
#define KQ_FMT 16384
#define KQ_INV 33792
#define KQ_BIA 34816
#define LDS_K 35840
__global__ __launch_bounds__(256, 2) void kqv_mfma(
    const char* __restrict__ xt2, const char* __restrict__ whi, const char* __restrict__ wlo,
    const float* __restrict__ gam, const float* __restrict__ bet,
    const float* __restrict__ mea, const float* __restrict__ var,
    char* __restrict__ qkT, char* __restrict__ vT) {
  __shared__ __attribute__((aligned(16))) char sm[LDS_K];
  int tid = threadIdx.x;
  int h0 = 64 * blockIdx.x, n = blockIdx.y;
  int lane = tid & 63, wv = tid >> 6, g = lane >> 4, l15 = lane & 15;
  const char* src = xt2 + (size_t)n * 32768 + h0 * 256;
  for (int i = tid; i < 1024; i += 256)
    ((f32x4*)(sm + KQ_XS))[i] = ((const f32x4*)src)[i];
  {
    float gv = gam[tid], bb = bet[tid], mm = mea[tid], vv = var[tid];
    float inv = gv * rsqrtf(vv + 1e-5f);
    ((float*)(sm + KQ_INV))[tid] = inv;
    ((float*)(sm + KQ_BIA))[tid] = bb - mm * inv;
  }
  __syncthreads();
  f32x4 acc[4][4];
#pragma unroll
  for (int a = 0; a < 4; a++)
#pragma unroll
    for (int b = 0; b < 4; b++) acc[a][b] = (f32x4){0.f, 0.f, 0.f, 0.f};
  const char* wsel = (g & 1) ? wlo : whi;
  int cofs = (g >> 1) * 8;
#pragma unroll
  for (int kk = 0; kk < 8; kk++) {
    h8 af[4], bf[4];
#pragma unroll
    for (int tt = 0; tt < 4; tt++)
      af[tt] = *(const h8*)(wsel + (64 * wv + 16 * tt + l15) * 256 + (16 * kk + cofs) * 2);
#pragma unroll
    for (int ht = 0; ht < 4; ht++)
      bf[ht] = *(const h8*)(sm + KQ_XS + (16 * ht + l15) * 256 +
                            (((2 * kk + (g >> 1)) ^ (l15 & 7)) << 4));
#pragma unroll
    for (int tt = 0; tt < 4; tt++)
#pragma unroll
      for (int ht = 0; ht < 4; ht++)
        acc[tt][ht] = __builtin_amdgcn_mfma_f32_16x16x32_f16(af[tt], bf[ht], acc[tt][ht], 0, 0, 0);
  }
  for (int r = 0; r < 4; r++) {
    if (wv == r) {
#pragma unroll
      for (int tt = 0; tt < 4; tt++)
#pragma unroll
        for (int ht = 0; ht < 4; ht++) {
          int ob = 16 * tt + 4 * g;
#pragma unroll
          for (int i = 0; i < 4; i++) {
            int o = 64 * r + ob + i;
            float inv = ((float*)(sm + KQ_INV))[o];
            float bia = ((float*)(sm + KQ_BIA))[o];
            ((float*)(sm + KQ_FMT))[(ob + i) * 68 + 16 * ht + l15] = acc[tt][ht][i] * inv + bia;
          }
        }
    }
    __syncthreads();
    {  // QK planes: Khi@0, Klo@2048, Qhi@4096, Qlo@6144 per (n,head)
      int xl = tid & 63, hsel = (tid >> 6) & 1, kq = tid >> 7;
      int headi = 2 * r + hsel;
      int obl = hsel * 32 + kq * 8;
      u16x8 hi8, lo8;
#pragma unroll
      for (int d = 0; d < 8; d++) {
        float v = ((float*)(sm + KQ_FMT))[(obl + d) * 68 + xl];
        u16 hb = f2b(v);
        hi8[d] = hb;
        lo8[d] = f2b(v - b2f(hb));
      }
      char* dsth = qkT + (size_t)(n * 8 + headi) * 8192 + (kq * 2) * 2048 + (h0 + xl) * 16;
      *(u16x8*)dsth = hi8;
      *(u16x8*)(dsth + 2048) = lo8;
    }
    {  // V: [16 d][128 x] f16
      int hsel = tid >> 7, d = (tid >> 3) & 15, xo = tid & 7;
      int headi = 2 * r + hsel;
      h8 vv;
#pragma unroll
      for (int j = 0; j < 8; j++)
        vv[j] = (_Float16)((float*)(sm + KQ_FMT))[(hsel * 32 + 16 + d) * 68 + xo * 8 + j];
      *(h8*)(vT + (size_t)(n * 8 + headi) * 4096 + d * 256 + (h0 + xo * 8) * 2) = vv;
    }
    __syncthreads();
  }
}

// ---------------- attention v4: barrier-free, wave-private scratch, 4 blocks/CU ----------------
// per-wave scratch 9472B, phase-aliased:
//   R1: f32 [16 x][148 dw] stride 592       (9472B)
//   R2: 4 bufs f16 [16 y][52] stride 104    (6656B)
//   Pun: f16 [32 j][136] stride 272         (8704B)
//   Psk: f16 [16 j][168] stride 336         (5376B)
#define SW_BYTES 9472
#define T1_STRIDE 592
#define LDS_A 37888
__global__ __launch_bounds__(256, 4) void attn_mfma4(
    const char* __restrict__ qkT, const char* __restrict__ vT, const char* __restrict__ relT,
    const float* __restrict__ lg, const float* __restrict__ lb,
    const float* __restrict__ lm, const float* __restrict__ lv,
    _Float16* __restrict__ otmp) {
  __shared__ __attribute__((aligned(16))) char sm[LDS_A];
  const int tid = threadIdx.x;
  const int head = blockIdx.x, n = blockIdx.y;
  const int lane = tid & 63, wv = tid >> 6;
  const int g = lane >> 4, l15 = lane & 15;
  char* sw = sm + wv * SW_BYTES;
  const char* qkb = qkT + (size_t)(n * 8 + head) * 8192;
  const char* vb = vT + (size_t)(n * 8 + head) * 4096;
  // A-side hi/lo by (g&1) = (hi,lo,hi,lo); B-side by (g>>1) = (hi,hi,lo,lo)
  const char* kAp = qkb + ((g & 1) ? 2048 : 0);
  const char* kBp = qkb + ((g >> 1) ? 2048 : 0);
  const char* qBp = qkb + 4096 + ((g >> 1) ? 2048 : 0);
  const char* eqA = relT + ((g & 1) ? 4096 : 0);
  const char* ekA = relT + 8192 + ((g & 1) ? 4096 : 0);
  const char* veB = relT + 16384;  // [16 d][512 h], stride 1024B

  float a0 = lg[head] * rsqrtf(lv[head] + 1e-5f);
  float a1 = lg[8 + head] * rsqrtf(lv[8 + head] + 1e-5f);
  float a2 = lg[16 + head] * rsqrtf(lv[16 + head] + 1e-5f);
  float bsum = (lb[head] - lm[head] * a0) + (lb[8 + head] - lm[8 + head] * a1) +
               (lb[16 + head] - lm[16 + head] * a2);

  const f32x4 zero4 = {0.f, 0.f, 0.f, 0.f};
  const int X0a = 32 * wv, X0b = X0a + 16;

  // ---- S0: lane holds S[x = X0+l15][y = 16yt+4g+i] (A=k, B=q) ----
  s8v qfA = *(const s8v*)(qBp + (X0a + l15) * 16);
  s8v qfB = *(const s8v*)(qBp + (X0b + l15) * 16);
  f32x4 s0[8], s1[8];
#pragma unroll
  for (int yt = 0; yt < 8; yt++) {
    s8v ka = *(const s8v*)(kAp + (yt * 16 + l15) * 16);
    f32x4 d0 = __builtin_amdgcn_mfma_f32_16x16x32_bf16(ka, qfA, zero4, 0, 0, 0);
    f32x4 d1 = __builtin_amdgcn_mfma_f32_16x16x32_bf16(ka, qfB, zero4, 0, 0, 0);
#pragma unroll
    for (int i = 0; i < 4; i++) {
      s0[yt][i] = a0 * d0[i] + bsum;
      s1[yt][i] = a0 * d1[i] + bsum;
    }
  }

  // ---- R1: Rq[r][x]; f32 scratch [16 x][148dw], transposed reads ----
  {
    s8v eqf[10];
    int rbu = 96 - X0a;  // tile-a uses t+1, tile-b uses t
#pragma unroll
    for (int t = 0; t < 10; t++)
      eqf[t] = *(const s8v*)(eqA + (rbu + 16 * t + l15) * 16);
#pragma unroll
    for (int t = 0; t < 9; t++) {
      f32x4 d = __builtin_amdgcn_mfma_f32_16x16x32_bf16(eqf[t + 1], qfA, zero4, 0, 0, 0);
      *(f32x4*)(sw + l15 * T1_STRIDE + (16 * t + 4 * g) * 4) = d;
    }
    {
      const float* r1p = (const float*)(sw + l15 * T1_STRIDE) + (4 * g + 15 - l15);
#pragma unroll
      for (int yt = 0; yt < 8; yt++)
#pragma unroll
        for (int i = 0; i < 4; i++) s0[yt][i] += a1 * r1p[16 * yt + i];
    }
#pragma unroll
    for (int t = 0; t < 9; t++) {
      f32x4 d = __builtin_amdgcn_mfma_f32_16x16x32_bf16(eqf[t], qfB, zero4, 0, 0, 0);
      *(f32x4*)(sw + l15 * T1_STRIDE + (16 * t + 4 * g) * 4) = d;
    }
    {
      const float* r1p = (const float*)(sw + l15 * T1_STRIDE) + (4 * g + 15 - l15);
#pragma unroll
      for (int yt = 0; yt < 8; yt++)
#pragma unroll
        for (int i = 0; i < 4; i++) s1[yt][i] += a1 * r1p[16 * yt + i];
    }
  }

  // ---- R2: per-wave band, Rk[y][r] window rb2 = X0a-16yt+112, width 47 (3 K-tiles) ----
  // scratch: 4 rolling bufs [16 y][52 h] stride 104B; produce 4 strips, then consume.
#pragma unroll
  for (int grp = 0; grp < 2; grp++) {
#pragma unroll
    for (int q4 = 0; q4 < 4; q4++) {
      int yt = grp * 4 + q4;
      int rb2 = X0a - 16 * yt + 112;
      char* buf = sw + q4 * 1664;
      s8v kf = *(const s8v*)(kBp + (16 * yt + l15) * 16);
#pragma unroll
      for (int t = 0; t < 3; t++) {
        s8v ef = *(const s8v*)(ekA + (rb2 + 16 * t + l15) * 16);
        f32x4 d = __builtin_amdgcn_mfma_f32_16x16x32_bf16(ef, kf, zero4, 0, 0, 0);
        h4 hv;
#pragma unroll
        for (int i = 0; i < 4; i++) hv[i] = (_Float16)d[i];
        *(h4*)(buf + l15 * 104 + (16 * t + 4 * g) * 2) = hv;
      }
    }
#pragma unroll
    for (int q4 = 0; q4 < 4; q4++) {
      int yt = grp * 4 + q4;
      const char* buf = sw + q4 * 1664;
#pragma unroll
      for (int i = 0; i < 4; i++) {
        const char* bp = buf + (4 * g + i) * 104 + (l15 + 15 - 4 * g - i) * 2;
        float v0 = (float)*(const _Float16*)bp;         // tile a
        float v1 = (float)*(const _Float16*)(bp + 32);  // tile b (+16 cols)
        s0[yt][i] += a2 * v0;
        s1[yt][i] += a2 * v1;
      }
    }
  }

  // ---- softmax (row x per lane; reduce across g via shfl_xor 16,32) ----
  float rl0, rl1;
  {
    float m0 = -1e30f, m1 = -1e30f;
#pragma unroll
    for (int yt = 0; yt < 8; yt++)
#pragma unroll
      for (int i = 0; i < 4; i++) {
        m0 = fmaxf(m0, s0[yt][i]);
        m1 = fmaxf(m1, s1[yt][i]);
      }
    m0 = fmaxf(m0, __shfl_xor(m0, 16)); m0 = fmaxf(m0, __shfl_xor(m0, 32));
    m1 = fmaxf(m1, __shfl_xor(m1, 16)); m1 = fmaxf(m1, __shfl_xor(m1, 32));
    float l0 = 0.f, l1 = 0.f;
#pragma unroll
    for (int yt = 0; yt < 8; yt++)
#pragma unroll
      for (int i = 0; i < 4; i++) {
        float p0 = __expf(s0[yt][i] - m0); s0[yt][i] = p0; l0 += p0;
        float p1 = __expf(s1[yt][i] - m1); s1[yt][i] = p1; l1 += p1;
      }
    l0 += __shfl_xor(l0, 16); l0 += __shfl_xor(l0, 32);
    l1 += __shfl_xor(l1, 16); l1 += __shfl_xor(l1, 32);
    rl0 = 1.f / l0; rl1 = 1.f / l1;
  }

  // ---- Pun stores: [32 j][136 h] stride 272 (j = l15 tile-a, 16+l15 tile-b) ----
#pragma unroll
  for (int yt = 0; yt < 8; yt++) {
    char* pa = sw + l15 * 272 + (16 * yt + 4 * g) * 2;
    *(u32*)pa = packh2(s0[yt][0], s0[yt][1]);
    *(u32*)(pa + 4) = packh2(s0[yt][2], s0[yt][3]);
    char* pb = sw + (16 + l15) * 272 + (16 * yt + 4 * g) * 2;
    *(u32*)pb = packh2(s1[yt][0], s1[yt][1]);
    *(u32*)(pb + 4) = packh2(s1[yt][2], s1[yt][3]);
  }
  // ---- PV: A=V (global), B=Pun rows ----
  f32x4 acc0 = zero4, acc1 = zero4;
#pragma unroll
  for (int ky = 0; ky < 4; ky++) {
    h8 vf = *(const h8*)(vb + l15 * 256 + (32 * ky + 8 * g) * 2);
    h8 p0 = *(const h8*)(sw + l15 * 272 + (32 * ky + 8 * g) * 2);
    h8 p1 = *(const h8*)(sw + (16 + l15) * 272 + (32 * ky + 8 * g) * 2);
    acc0 = __builtin_amdgcn_mfma_f32_16x16x32_f16(vf, p0, acc0, 0, 0, 0);
    acc1 = __builtin_amdgcn_mfma_f32_16x16x32_f16(vf, p1, acc1, 0, 0, 0);
  }

  // ---- PVenc: Psk [16 j][168] stride 336, zero once, per-tile store+5 MFMA ----
  for (int i = lane; i < 336; i += 64) *(f32x4*)(sw + i * 16) = zero4;  // 5376B zero
  {  // tile a
#pragma unroll
    for (int yt = 0; yt < 8; yt++)
#pragma unroll
      for (int i = 0; i < 4; i++) {
        int col = 16 * yt + 4 * g + i - l15 + 15;
        *(u16*)(sw + l15 * 336 + col * 2) = f2h_bits(s0[yt][i]);
      }
    int rb_a = 112 - X0a;
#pragma unroll
    for (int t = 0; t < 5; t++) {
      h8 vef = *(const h8*)(veB + l15 * 1024 + (rb_a + 32 * t + 8 * g) * 2);
      h8 skf = *(const h8*)(sw + l15 * 336 + (32 * t + 8 * g) * 2);
      acc0 = __builtin_amdgcn_mfma_f32_16x16x32_f16(vef, skf, acc0, 0, 0, 0);
    }
  }
  {  // tile b (full data-region overwrite; pads stay zero)
#pragma unroll
    for (int yt = 0; yt < 8; yt++)
#pragma unroll
      for (int i = 0; i < 4; i++) {
        int col = 16 * yt + 4 * g + i - l15 + 15;
        *(u16*)(sw + l15 * 336 + col * 2) = f2h_bits(s1[yt][i]);
      }
    int rb_b = 96 - X0a;
#pragma unroll
    for (int t = 0; t < 5; t++) {
      h8 vef = *(const h8*)(veB + l15 * 1024 + (rb_b + 32 * t + 8 * g) * 2);
      h8 skf = *(const h8*)(sw + l15 * 336 + (32 * t + 8 * g) * 2);
      acc1 = __builtin_amdgcn_mfma_f32_16x16x32_f16(vef, skf, acc1, 0, 0, 0);
    }
  }

  // ---- normalize + write otmp[n][c][x] f16 ----
  size_t obase = (size_t)(n * 8 + head) * 2048;
#pragma unroll
  for (int i = 0; i < 4; i++) {
    int d = 4 * g + i;
    otmp[obase + d * 128 + X0a + l15] = (_Float16)(acc0[i] * rl0);
    otmp[obase + d * 128 + X0b + l15] = (_Float16)(acc1[i] * rl1);
  }
}

// ---------------- otmp f16 -> out f32 transpose ----------------
__global__ __launch_bounds__(256) void transpose_h2f(
    const u16* __restrict__ src, float* __restrict__ dst,
    int sb, int sc, int sstr, int db, int dc, int dstr) {
  __shared__ u16 tile[32][33];
  int z = blockIdx.z, b = z >> 7, c = z & 127;
  const u16* s = src + (size_t)b * sb + c * sc;
  float* d = dst + (size_t)b * db + c * dc;
  int tx = threadIdx.x, ty = threadIdx.y;
  int r0 = blockIdx.y * 32, c0 = blockIdx.x * 32;
#pragma unroll
  for (int k = 0; k < 4; k++)
    tile[ty + k * 8][tx] = s[(size_t)(r0 + ty + k * 8) * sstr + c0 + tx];
  __syncthreads();
#pragma unroll
  for (int k = 0; k < 4; k++) {
    u16 hv = tile[tx][ty + k * 8];
    d[(size_t)(c0 + ty + k * 8) * dstr + r0 + tx] = (float)(*(const _Float16*)&hv);
  }
}

extern "C" void kernel_launch(void* const* d_in, const int* in_sizes, int n_in,
                              void* d_out, int out_size, void* d_ws, size_t ws_size,
                              hipStream_t stream) {
  const float* x     = (const float*)d_in[0];
  const float* kqv_w = (const float*)d_in[1];
  const float* kqv_g = (const float*)d_in[2];
  const float* kqv_b = (const float*)d_in[3];
  const float* kqv_m = (const float*)d_in[4];
  const float* kqv_v = (const float*)d_in[5];
  const float* lg    = (const float*)d_in[6];
  const float* lb    = (const float*)d_in[7];
  const float* lm    = (const float*)d_in[8];
  const float* lv    = (const float*)d_in[9];
  const float* rel   = (const float*)d_in[10];
  float* out = (float*)d_out;

  char* ws = (char*)d_ws;
  char* xt2  = ws;                              //  8 MiB f16 swizzled [n][h][c]
  char* qkT  = ws + 8388608;                    // 16 MiB bf16 hi/lo planes
  char* vT   = ws + 25165824;                   //  8 MiB f16 [n,h][d][x]
  _Float16* otmp = (_Float16*)(ws + 33554432);  //  8 MiB f16
  char* whi  = ws + 41943040;                   // 64 KiB
  char* wlo  = ws + 42008576;                   // 64 KiB
  char* relT = ws + 42074112;                   // 32 KiB

  prep_tables<<<33, 256, 0, stream>>>(kqv_w, rel, whi, wlo, relT);
  transpose_x<<<dim3(4, 4, 256), dim3(32, 8), 0, stream>>>(x, xt2);
  kqv_mfma<<<dim3(2, 256), 256, 0, stream>>>(xt2, whi, wlo, kqv_g, kqv_b, kqv_m, kqv_v, qkT, vT);
  attn_mfma4<<<dim3(8, 256), 256, 0, stream>>>(qkT, vT, relT, lg, lb, lm, lv, otmp);
  transpose_h2f<<<dim3(4, 4, 256), dim3(32, 8), 0, stream>>>(
      (const u16*)otmp, out, 2097152, 128, 16384, 2097152, 16384, 128);
}